// Round 1
// baseline (1687.768 us; speedup 1.0000x reference)
//
#include <hip/hip_runtime.h>
#include <hip/hip_fp16.h>

#define N_NODES 100000
#define N_EDGES 3200000
#define N_GRAPHS 5000
#define BN_EPS 1e-5f
#define HPAD 80        // hidden 75 padded to 80
#define CHUNK 2048     // edges per bucket-sort block
#define NBLKA 1563     // ceil(N_EDGES / CHUNK)
#define NBKT 782       // buckets of 128 nodes (dst >> 7)
#define LROW 33        // LDS accumulator row stride (pad breaks bank alignment)
#define NS1 4775       // ceil(NBKT*NBLKA / 256)  (782*1563 = 1222266)
#define LALLOC (NS1 * 256)
#define VPT 19         // ceil(NS1 / 256) for ks2
#define W1S 36         // sW1 row stride: 2-way bank alias only (free)

// ---------- node encoder: h = x @ node_w + node_b (fp32 + fp16 mirror) ----------
__global__ void k_encode(const float* __restrict__ x, const float* __restrict__ W,
                         const float* __restrict__ b, float* __restrict__ h,
                         __half* __restrict__ h16) {
    __shared__ float sW[448];
    __shared__ float sb[32];
    for (int i = threadIdx.x; i < 448; i += 256) sW[i] = W[i];
    if (threadIdx.x < 32) sb[threadIdx.x] = b[threadIdx.x];
    __syncthreads();
    int n = blockIdx.x * 256 + threadIdx.x;
    if (n >= N_NODES) return;
    float xi[14];
#pragma unroll
    for (int k = 0; k < 14; k++) xi[k] = x[n * 14 + k];
    float4* hp = (float4*)(h + (size_t)n * 32);
    __half2* hq = (__half2*)(h16 + (size_t)n * 32);
#pragma unroll
    for (int q = 0; q < 8; q++) {
        float4 acc;
        float* ap = (float*)&acc;
#pragma unroll
        for (int i = 0; i < 4; i++) {
            int c = q * 4 + i;
            float a = sb[c];
#pragma unroll
            for (int k = 0; k < 14; k++) a += xi[k] * sW[k * 32 + c];
            ap[i] = a;
        }
        hp[q] = acc;
        hq[q * 2 + 0] = __floats2half2_rn(acc.x, acc.y);
        hq[q * 2 + 1] = __floats2half2_rn(acc.z, acc.w);
    }
}

// ---------- weight prep ----------
__global__ void k_prep(const float* __restrict__ W1, const float* __restrict__ b1,
                       const float* __restrict__ W2,
                       float* __restrict__ w1tp, float* __restrict__ b1p,
                       float* __restrict__ w2p) {
    int i = blockIdx.x * 256 + threadIdx.x;
    if (i < 2 * HPAD * 32) {
        int l = i / (HPAD * 32), r = i % (HPAD * 32);
        int j = r / 32, c = r % 32;
        w1tp[i] = (j < 75) ? W1[l * 2400 + c * 75 + j] : 0.f;
        w2p[i]  = (j < 75) ? W2[l * 2400 + j * 32 + c] : 0.f;
    } else if (i < 2 * HPAD * 32 + 2 * HPAD) {
        int k = i - 2 * HPAD * 32;
        int l = k / HPAD, j = k % HPAD;
        b1p[k] = (j < 75) ? b1[l * 75 + j] : 0.f;
    }
}

// ---------- bucket sort phase A: per-chunk histogram over 782 buckets ----------
__global__ void __launch_bounds__(256) ksA(const int* __restrict__ ei, int* __restrict__ cmat) {
    __shared__ int lh[NBKT];
    for (int i = threadIdx.x; i < NBKT; i += 256) lh[i] = 0;
    __syncthreads();
    int b0 = blockIdx.x * CHUNK;
    for (int i = threadIdx.x; i < CHUNK; i += 256) {
        int e = b0 + i;
        if (e < N_EDGES) atomicAdd(&lh[ei[N_EDGES + e] >> 7], 1);
    }
    __syncthreads();
    for (int i = threadIdx.x; i < NBKT; i += 256)
        cmat[i * NBLKA + blockIdx.x] = lh[i];
}

// ---------- parallel exclusive scan of cmat ----------
__global__ void ks1(const int* __restrict__ a, int* __restrict__ bs) {
    __shared__ int s[256];
    int i = blockIdx.x * 256 + threadIdx.x;
    s[threadIdx.x] = a[i];
    __syncthreads();
    for (int o = 128; o > 0; o >>= 1) {
        if (threadIdx.x < o) s[threadIdx.x] += s[threadIdx.x + o];
        __syncthreads();
    }
    if (threadIdx.x == 0) bs[blockIdx.x] = s[0];
}

__global__ void ks2(int* __restrict__ bs) {
    __shared__ int s[256];
    int t = threadIdx.x;
    int v[VPT];
    int base = t * VPT, sum = 0;
#pragma unroll
    for (int k = 0; k < VPT; k++) {
        int idx = base + k;
        int x = (idx < NS1) ? bs[idx] : 0;
        v[k] = sum; sum += x;
    }
    s[t] = sum;
    __syncthreads();
    for (int o = 1; o < 256; o <<= 1) {
        int add = (t >= o) ? s[t - o] : 0;
        __syncthreads();
        s[t] += add;
        __syncthreads();
    }
    int excl = (t == 0) ? 0 : s[t - 1];
#pragma unroll
    for (int k = 0; k < VPT; k++) {
        int idx = base + k;
        if (idx < NS1) bs[idx] = excl + v[k];
    }
}

__global__ void ks3(int* __restrict__ a, const int* __restrict__ bs) {
    __shared__ int s[256];
    int t = threadIdx.x, i = blockIdx.x * 256 + t;
    int v = a[i];
    s[t] = v;
    __syncthreads();
    for (int o = 1; o < 256; o <<= 1) {
        int add = (t >= o) ? s[t - o] : 0;
        __syncthreads();
        s[t] += add;
        __syncthreads();
    }
    a[i] = s[t] - v + bs[blockIdx.x];
}

// ---------- phase B: per-block counting sort in LDS, then coalesced drain ----------
__global__ void __launch_bounds__(256) ksB(const int* __restrict__ ei, const float* __restrict__ ea,
                                           const int* __restrict__ cmat, float4* __restrict__ buf1) {
    __shared__ float4 rec[CHUNK];          // 32 KB
    __shared__ unsigned short sbkt[CHUNK]; // 4 KB
    __shared__ int lh[NBKT];
    __shared__ int lex[NBKT];
    __shared__ int gb[NBKT];
    __shared__ int sc[256];
    int t = threadIdx.x;
    int b0 = blockIdx.x * CHUNK;
    int nval = min(CHUNK, N_EDGES - b0);
    for (int i = t; i < NBKT; i += 256) lh[i] = 0;
    __syncthreads();
    for (int i = t; i < nval; i += 256)
        atomicAdd(&lh[ei[N_EDGES + b0 + i] >> 7], 1);
    __syncthreads();
    // scan over 782 buckets: 4 consecutive per thread, then 256-wide scan of thread totals
    int v[4]; int run = 0;
#pragma unroll
    for (int k = 0; k < 4; k++) {
        int idx = t * 4 + k;
        int x = (idx < NBKT) ? lh[idx] : 0;
        v[k] = run; run += x;
    }
    sc[t] = run;
    __syncthreads();
    for (int o = 1; o < 256; o <<= 1) {
        int add = (t >= o) ? sc[t - o] : 0;
        __syncthreads();
        sc[t] += add;
        __syncthreads();
    }
    int excl = (t == 0) ? 0 : sc[t - 1];
#pragma unroll
    for (int k = 0; k < 4; k++) {
        int idx = t * 4 + k;
        if (idx < NBKT) {
            int base = excl + v[k];
            lex[idx] = base;
            lh[idx] = base;          // running cursor
            gb[idx] = cmat[idx * NBLKA + blockIdx.x];
        }
    }
    __syncthreads();
    for (int i = t; i < nval; i += 256) {
        int e = b0 + i;
        int src = ei[e], dst = ei[N_EDGES + e];
        float a0 = ea[(size_t)e * 3 + 0], a1 = ea[(size_t)e * 3 + 1], a2 = ea[(size_t)e * 3 + 2];
        int bkt = dst >> 7;
        int r = atomicAdd(&lh[bkt], 1);
        rec[r] = make_float4(a0, a1, a2, __int_as_float(src | ((dst & 127) << 17)));
        sbkt[r] = (unsigned short)bkt;
    }
    __syncthreads();
    for (int p = t; p < nval; p += 256) {
        int bkt = sbkt[p];
        buf1[gb[bkt] + (p - lex[bkt])] = rec[p];
    }
}

// ---------- bucket-level aggregation: one 128-node bucket per block, LDS accumulator ----------
// replaces ksC + per-node-CSR k_agg: consumes buf1 directly, writes zin = h + agg
__global__ void __launch_bounds__(256) k_aggB(const int* __restrict__ cmat,
                                              const float4* __restrict__ buf1,
                                              const float* __restrict__ eW, const float* __restrict__ eb,
                                              const __half* __restrict__ h16,
                                              const float* __restrict__ h, float* __restrict__ zin) {
    __shared__ float acc[128 * LROW];   // 16.9 KB, pad 33 spreads dl*33+4q+i across banks
    int t = threadIdx.x;
    int g = blockIdx.x;
    for (int i = t; i < 128 * LROW; i += 256) acc[i] = 0.f;
    int q = t & 7, er = t >> 3;         // 32 edges per pass, 8 channel-slices per edge
    int c0 = q * 4;
    float w0[4], w1[4], w2[4], bb4[4];
#pragma unroll
    for (int i = 0; i < 4; i++) {
        w0[i] = eW[c0 + i];
        w1[i] = eW[32 + c0 + i];
        w2[i] = eW[64 + c0 + i];
        bb4[i] = eb[c0 + i];
    }
    int bb = cmat[g * NBLKA];
    int be = (g == NBKT - 1) ? N_EDGES : cmat[(g + 1) * NBLKA];
    __syncthreads();
    int j = bb + er;
    for (; j + 32 < be; j += 64) {      // unroll-2: two independent gather chains
        float4 pa = buf1[j];
        float4 pb = buf1[j + 32];
        int ba = __float_as_int(pa.w), bbts = __float_as_int(pb.w);
        float2 ra = *(const float2*)(h16 + (size_t)(ba & 0x1FFFF) * 32 + c0);
        float2 rb = *(const float2*)(h16 + (size_t)(bbts & 0x1FFFF) * 32 + c0);
        float2 a01 = __half22float2(*(__half2*)&ra.x);
        float2 a23 = __half22float2(*(__half2*)&ra.y);
        float2 b01 = __half22float2(*(__half2*)&rb.x);
        float2 b23 = __half22float2(*(__half2*)&rb.y);
        float ha4[4] = {a01.x, a01.y, a23.x, a23.y};
        float hb4[4] = {b01.x, b01.y, b23.x, b23.y};
        int da = (ba >> 17) * LROW + c0;
        int db = (bbts >> 17) * LROW + c0;
#pragma unroll
        for (int i = 0; i < 4; i++) {
            float ma = fmaxf(ha4[i] + pa.x * w0[i] + pa.y * w1[i] + pa.z * w2[i] + bb4[i], 0.f);
            float mb = fmaxf(hb4[i] + pb.x * w0[i] + pb.y * w1[i] + pb.z * w2[i] + bb4[i], 0.f);
            atomicAdd(&acc[da + i], ma);
            atomicAdd(&acc[db + i], mb);
        }
    }
    if (j < be) {
        float4 p = buf1[j];
        int bits = __float_as_int(p.w);
        float2 r = *(const float2*)(h16 + (size_t)(bits & 0x1FFFF) * 32 + c0);
        float2 a01 = __half22float2(*(__half2*)&r.x);
        float2 a23 = __half22float2(*(__half2*)&r.y);
        float hp4[4] = {a01.x, a01.y, a23.x, a23.y};
        int d = (bits >> 17) * LROW + c0;
#pragma unroll
        for (int i = 0; i < 4; i++) {
            float m = fmaxf(hp4[i] + p.x * w0[i] + p.y * w1[i] + p.z * w2[i] + bb4[i], 0.f);
            atomicAdd(&acc[d + i], m);
        }
    }
    __syncthreads();
    // epilogue: zin = h + acc for the 128 nodes, coalesced float4
    int n0 = g << 7;
    for (int idx = t; idx < 128 * 8; idx += 256) {
        int ln = idx >> 3, qq = idx & 7;
        int n = n0 + ln;
        if (n < N_NODES) {
            const float* ap = &acc[ln * LROW + qq * 4];
            float4 hv = *(const float4*)(h + (size_t)n * 32 + qq * 4);
            *(float4*)(zin + (size_t)n * 32 + qq * 4) =
                make_float4(ap[0] + hv.x, ap[1] + hv.y, ap[2] + hv.z, ap[3] + hv.w);
        }
    }
}

// ---------- fused MLP: z = relu(zin@W1+b1)@W2+b2, written over zin ----------
__global__ void __launch_bounds__(256, 4) k_mlp(float* __restrict__ zio,
                                                const float* __restrict__ W1, const float* __restrict__ B1,
                                                const float* __restrict__ W2, const float* __restrict__ b2) {
    __shared__ float sW1[HPAD * W1S];  // stride 36 (2-way bank alias = free)
    __shared__ float sW2[2560];
    __shared__ float sB1[80];
    __shared__ float sb2[32];
    __shared__ float hidL[32 * 84];
    for (int i = threadIdx.x; i < 2560; i += 256) {
        int j = i >> 5, c = i & 31;
        sW1[j * W1S + c] = W1[i];
        sW2[i] = W2[i];
    }
    if (threadIdx.x < 80) sB1[threadIdx.x] = B1[threadIdx.x];
    if (threadIdx.x < 32) sb2[threadIdx.x] = b2[threadIdx.x];
    __syncthreads();
    unsigned t = blockIdx.x * 256 + threadIdx.x;
    unsigned lane = threadIdx.x & 63;
    unsigned wv = threadIdx.x >> 6;
    unsigned oct = lane >> 3;
    unsigned nd = lane & 7;
    unsigned n = (t >> 6) * 8 + nd;
    const float4* ap = (const float4*)(zio + (size_t)n * 32);
    float zc[32];
#pragma unroll
    for (int q = 0; q < 8; q++) {
        float4 av = ap[q];
        zc[q * 4 + 0] = av.x;
        zc[q * 4 + 1] = av.y;
        zc[q * 4 + 2] = av.z;
        zc[q * 4 + 3] = av.w;
    }
    float hid[10];
#pragma unroll
    for (int i = 0; i < 10; i++) {
        int j = (int)oct * 10 + i;
        const float4* wp = (const float4*)(sW1 + j * W1S);
        float a0 = 0.f, a1 = 0.f, a2 = 0.f, a3 = 0.f;
#pragma unroll
        for (int q = 0; q < 8; q++) {
            float4 wv4 = wp[q];
            a0 += zc[q * 4 + 0] * wv4.x;
            a1 += zc[q * 4 + 1] * wv4.y;
            a2 += zc[q * 4 + 2] * wv4.z;
            a3 += zc[q * 4 + 3] * wv4.w;
        }
        hid[i] = fmaxf(sB1[j] + ((a0 + a1) + (a2 + a3)), 0.f);
    }
    float* hrow = &hidL[(wv * 8 + nd) * 84];
#pragma unroll
    for (int i = 0; i < 10; i++) hrow[oct * 10 + i] = hid[i];
    float4 zo = *(const float4*)(sb2 + oct * 4);
    const float4* hv4 = (const float4*)hrow;
#pragma unroll
    for (int k = 0; k < 20; k++) {
        float4 hv = hv4[k];
        const float* wr = sW2 + (k * 4) * 32 + oct * 4;
        float4 wa = *(const float4*)(wr);
        float4 wb = *(const float4*)(wr + 32);
        float4 wc = *(const float4*)(wr + 64);
        float4 wd = *(const float4*)(wr + 96);
        zo.x += hv.x * wa.x + hv.y * wb.x + hv.z * wc.x + hv.w * wd.x;
        zo.y += hv.x * wa.y + hv.y * wb.y + hv.z * wc.y + hv.w * wd.y;
        zo.z += hv.x * wa.z + hv.y * wb.z + hv.z * wc.z + hv.w * wd.z;
        zo.w += hv.x * wa.w + hv.y * wb.w + hv.z * wc.w + hv.w * wd.w;
    }
    *(float4*)(zio + (size_t)n * 32 + oct * 4) = zo;
}

// ---------- BN stats ----------
__global__ void __launch_bounds__(256) k_stats(const float* __restrict__ z, float* __restrict__ stats) {
    __shared__ float ls[4 * 64];
    int tid = threadIdx.x;
    int c = tid & 31;
    float s = 0.f, s2 = 0.f;
    for (int e = blockIdx.x * 256 + tid; e < N_NODES * 32; e += 256 * 256) {
        float v = z[e];
        s += v; s2 += v * v;
    }
    s += __shfl_down(s, 32, 64);
    s2 += __shfl_down(s2, 32, 64);
    int wave = tid >> 6, lane = tid & 63;
    if (lane < 32) { ls[wave * 64 + c] = s; ls[wave * 64 + 32 + c] = s2; }
    __syncthreads();
    if (tid < 64) {
        float a = ls[tid] + ls[64 + tid] + ls[128 + tid] + ls[192 + tid];
        atomicAdd(&stats[tid], a);
    }
}

// ---------- BN apply + relu (fp32 h + optional fp16 mirror) ----------
__global__ void k_bn(const float* __restrict__ z, float* __restrict__ h,
                     __half* __restrict__ h16,
                     const float* __restrict__ stats, const float* __restrict__ g,
                     const float* __restrict__ b, int write16) {
    int t = blockIdx.x * 256 + threadIdx.x;
    if (t >= N_NODES * 8) return;
    int q = t & 7;
    float4 zv = ((const float4*)z)[t];
    float* zp = (float*)&zv;
    float4 ov;
    float* op = (float*)&ov;
    const float invN = 1.0f / (float)N_NODES;
#pragma unroll
    for (int i = 0; i < 4; i++) {
        int c = q * 4 + i;
        float mu = stats[c] * invN;
        float var = stats[32 + c] * invN - mu * mu;
        float sc = g[c] / sqrtf(var + BN_EPS);
        op[i] = fmaxf((zp[i] - mu) * sc + b[c], 0.f);
    }
    ((float4*)h)[t] = ov;
    if (write16) {
        __half2 p0 = __floats2half2_rn(ov.x, ov.y);
        __half2 p1 = __floats2half2_rn(ov.z, ov.w);
        __half2* hq = (__half2*)(h16 + (size_t)t * 4);
        hq[0] = p0;
        hq[1] = p1;
    }
}

// ---------- graph offsets (batch is sorted) ----------
__global__ void k_goff(const int* __restrict__ batch, int* __restrict__ goff) {
    int g = blockIdx.x * 256 + threadIdx.x;
    if (g > N_GRAPHS) return;
    int lo = 0, hi = N_NODES;
    while (lo < hi) {
        int mid = (lo + hi) >> 1;
        if (batch[mid] < g) lo = mid + 1; else hi = mid;
    }
    goff[g] = lo;
}

// ---------- mean-pool: one wave per graph ----------
__global__ void __launch_bounds__(256) k_pool2(const float* __restrict__ h, const int* __restrict__ goff,
                                               float* __restrict__ gsum) {
    int wid = threadIdx.x >> 6, lane = threadIdx.x & 63;
    int g = blockIdx.x * 4 + wid;
    if (g >= N_GRAPHS) return;
    int s = goff[g], e = goff[g + 1];
    int c = lane & 31, half = lane >> 5;
    float acc = 0.f;
    for (int n = s + half; n < e; n += 2) acc += h[(size_t)n * 32 + c];
    acc += __shfl_down(acc, 32, 64);
    if (lane < 32) gsum[(size_t)g * 32 + c] = acc;
}

__global__ void k_head(const float* __restrict__ gsum, const int* __restrict__ goff,
                       const float* __restrict__ W1, const float* __restrict__ b1,
                       const float* __restrict__ W2, const float* __restrict__ b2,
                       float* __restrict__ out) {
    __shared__ float sW1[512], sb1[16], sW2[32], sb2[2];
    for (int i = threadIdx.x; i < 512; i += 256) sW1[i] = W1[i];
    if (threadIdx.x < 16) sb1[threadIdx.x] = b1[threadIdx.x];
    if (threadIdx.x < 32) sW2[threadIdx.x] = W2[threadIdx.x];
    if (threadIdx.x < 2) sb2[threadIdx.x] = b2[threadIdx.x];
    __syncthreads();
    int gI = blockIdx.x * 256 + threadIdx.x;
    if (gI >= N_GRAPHS) return;
    float cnt = (float)(goff[gI + 1] - goff[gI]);
    float inv = 1.0f / fmaxf(cnt, 1.0f);
    float gx[32];
#pragma unroll
    for (int c = 0; c < 32; c++) gx[c] = gsum[(size_t)gI * 32 + c] * inv;
    float hid[16];
#pragma unroll
    for (int j = 0; j < 16; j++) {
        float a = sb1[j];
#pragma unroll
        for (int c = 0; c < 32; c++) a += gx[c] * sW1[c * 16 + j];
        hid[j] = fmaxf(a, 0.f);
    }
#pragma unroll
    for (int o = 0; o < 2; o++) {
        float a = sb2[o];
#pragma unroll
        for (int j = 0; j < 16; j++) a += hid[j] * sW2[j * 2 + o];
        out[(size_t)gI * 2 + o] = a;
    }
}

extern "C" void kernel_launch(void* const* d_in, const int* in_sizes, int n_in,
                              void* d_out, int out_size, void* d_ws, size_t ws_size,
                              hipStream_t stream) {
    const float* x       = (const float*)d_in[0];
    const int*   ei      = (const int*)d_in[1];
    const float* eattr   = (const float*)d_in[2];
    const int*   batch   = (const int*)d_in[3];
    const float* node_w  = (const float*)d_in[4];
    const float* node_b  = (const float*)d_in[5];
    const float* edge_w  = (const float*)d_in[6];
    const float* edge_b  = (const float*)d_in[7];
    const float* conv_w1 = (const float*)d_in[8];
    const float* conv_b1 = (const float*)d_in[9];
    const float* conv_w2 = (const float*)d_in[10];
    const float* conv_b2 = (const float*)d_in[11];
    const float* bn_g    = (const float*)d_in[12];
    const float* bn_b    = (const float*)d_in[13];
    const float* lin1_w  = (const float*)d_in[14];
    const float* lin1_b  = (const float*)d_in[15];
    const float* lin2_w  = (const float*)d_in[16];
    const float* lin2_b  = (const float*)d_in[17];
    float* out = (float*)d_out;

    float4* buf1   = (float4*)d_ws;                        // 51.2 MB (bucket-sorted edges)
    float*  h      = (float*)(buf1 + N_EDGES);             // 12.8 MB
    float*  agg    = h + (size_t)N_NODES * 32;             // 12.8 MB (zin / z in-place)
    __half* h16    = (__half*)(agg + (size_t)N_NODES * 32);// 6.4 MB
    int*    cmat   = (int*)(h16 + (size_t)N_NODES * 32);   // LALLOC ints (~4.9 MB)
    int*    t1     = cmat + LALLOC;                        // NS1 (pad to 4864)
    int*    goff   = t1 + 4864;                            // N_GRAPHS+1
    float*  stats  = (float*)(goff + N_GRAPHS + 1);        // 64
    float*  gsum   = stats + 64;                           // G*32
    float*  w1tp   = gsum + (size_t)N_GRAPHS * 32;         // 2*80*32
    float*  b1p    = w1tp + 2 * HPAD * 32;                 // 2*80
    float*  w2p    = b1p + 2 * HPAD;                       // 2*80*32

    int nb_nodes = (N_NODES + 255) / 256;
    int nb_vec   = (N_NODES * 8 + 255) / 256;

    hipMemsetAsync(cmat, 0, LALLOC * sizeof(int), stream);
    k_encode<<<nb_nodes, 256, 0, stream>>>(x, node_w, node_b, h, h16);
    k_prep<<<(2 * HPAD * 32 + 2 * HPAD + 255) / 256, 256, 0, stream>>>(
        conv_w1, conv_b1, conv_w2, w1tp, b1p, w2p);
    k_goff<<<(N_GRAPHS + 1 + 255) / 256, 256, 0, stream>>>(batch, goff);

    ksA<<<NBLKA, 256, 0, stream>>>(ei, cmat);
    ks1<<<NS1, 256, 0, stream>>>(cmat, t1);
    ks2<<<1, 256, 0, stream>>>(t1);
    ks3<<<NS1, 256, 0, stream>>>(cmat, t1);
    ksB<<<NBLKA, 256, 0, stream>>>(ei, eattr, cmat, buf1);

    for (int l = 0; l < 2; l++) {
        hipMemsetAsync(stats, 0, 64 * sizeof(float), stream);
        k_aggB<<<NBKT, 256, 0, stream>>>(cmat, buf1, edge_w, edge_b, h16, h, agg);
        k_mlp<<<N_NODES * 8 / 256, 256, 0, stream>>>(agg, w1tp + l * HPAD * 32,
                                                     b1p + l * HPAD, w2p + l * HPAD * 32,
                                                     conv_b2 + l * 32);
        k_stats<<<256, 256, 0, stream>>>(agg, stats);
        k_bn<<<nb_vec, 256, 0, stream>>>(agg, h, h16, stats, bn_g + l * 32, bn_b + l * 32,
                                         l == 0 ? 1 : 0);
    }
    k_pool2<<<(N_GRAPHS + 3) / 4, 256, 0, stream>>>(h, goff, gsum);
    k_head<<<(N_GRAPHS + 255) / 256, 256, 0, stream>>>(gsum, goff, lin1_w, lin1_b, lin2_w, lin2_b, out);
}

// Round 2
// 746.402 us; speedup vs baseline: 2.2612x; 2.2612x over previous
//
#include <hip/hip_runtime.h>
#include <hip/hip_fp16.h>

#define N_NODES 100000
#define N_EDGES 3200000
#define N_GRAPHS 5000
#define BN_EPS 1e-5f
#define HPAD 80        // hidden 75 padded to 80
#define CHUNK 2048     // edges per bucket-sort block
#define NBLKA 1563     // ceil(N_EDGES / CHUNK)
#define NBKT 196       // buckets of 512 nodes (dst >> 9)
#define NPAD2 (NBKT * 512)   // 100352 = 392*256 exactly
#define NS1 1197       // ceil(NBKT*NBLKA / 256)
#define NSB 392        // NPAD2 / 256
#define LALLOC (NS1 * 256)
#define W1S 36         // sW1 row stride: 2-way bank alias only (free)
#define PSLICE 16      // placement sub-blocks per bucket

// ---------- node encoder: h = x @ node_w + node_b (fp32 + fp16 mirror) ----------
__global__ void k_encode(const float* __restrict__ x, const float* __restrict__ W,
                         const float* __restrict__ b, float* __restrict__ h,
                         __half* __restrict__ h16) {
    __shared__ float sW[448];
    __shared__ float sb[32];
    for (int i = threadIdx.x; i < 448; i += 256) sW[i] = W[i];
    if (threadIdx.x < 32) sb[threadIdx.x] = b[threadIdx.x];
    __syncthreads();
    int n = blockIdx.x * 256 + threadIdx.x;
    if (n >= N_NODES) return;
    float xi[14];
#pragma unroll
    for (int k = 0; k < 14; k++) xi[k] = x[n * 14 + k];
    float4* hp = (float4*)(h + (size_t)n * 32);
    __half2* hq = (__half2*)(h16 + (size_t)n * 32);
#pragma unroll
    for (int q = 0; q < 8; q++) {
        float4 acc;
        float* ap = (float*)&acc;
#pragma unroll
        for (int i = 0; i < 4; i++) {
            int c = q * 4 + i;
            float a = sb[c];
#pragma unroll
            for (int k = 0; k < 14; k++) a += xi[k] * sW[k * 32 + c];
            ap[i] = a;
        }
        hp[q] = acc;
        hq[q * 2 + 0] = __floats2half2_rn(acc.x, acc.y);
        hq[q * 2 + 1] = __floats2half2_rn(acc.z, acc.w);
    }
}

// ---------- weight prep ----------
__global__ void k_prep(const float* __restrict__ W1, const float* __restrict__ b1,
                       const float* __restrict__ W2,
                       float* __restrict__ w1tp, float* __restrict__ b1p,
                       float* __restrict__ w2p) {
    int i = blockIdx.x * 256 + threadIdx.x;
    if (i < 2 * HPAD * 32) {
        int l = i / (HPAD * 32), r = i % (HPAD * 32);
        int j = r / 32, c = r % 32;
        w1tp[i] = (j < 75) ? W1[l * 2400 + c * 75 + j] : 0.f;
        w2p[i]  = (j < 75) ? W2[l * 2400 + j * 32 + c] : 0.f;
    } else if (i < 2 * HPAD * 32 + 2 * HPAD) {
        int k = i - 2 * HPAD * 32;
        int l = k / HPAD, j = k % HPAD;
        b1p[k] = (j < 75) ? b1[l * 75 + j] : 0.f;
    }
}

// ---------- bucket sort phase A + per-node degree histogram ----------
__global__ void __launch_bounds__(256) ksA(const int* __restrict__ ei, int* __restrict__ cmat,
                                           int* __restrict__ nodeCnt) {
    __shared__ int lh[NBKT];
    if (threadIdx.x < NBKT) lh[threadIdx.x] = 0;
    __syncthreads();
    int b0 = blockIdx.x * CHUNK;
    for (int i = threadIdx.x; i < CHUNK; i += 256) {
        int e = b0 + i;
        if (e < N_EDGES) {
            int d = ei[N_EDGES + e];
            atomicAdd(&lh[d >> 9], 1);
            atomicAdd(&nodeCnt[d], 1);
        }
    }
    __syncthreads();
    if (threadIdx.x < NBKT) cmat[threadIdx.x * NBLKA + blockIdx.x] = lh[threadIdx.x];
}

// ---------- generic 3-kernel exclusive scan ----------
__global__ void ks1(const int* __restrict__ a, int* __restrict__ bs) {
    __shared__ int s[256];
    int i = blockIdx.x * 256 + threadIdx.x;
    s[threadIdx.x] = a[i];
    __syncthreads();
    for (int o = 128; o > 0; o >>= 1) {
        if (threadIdx.x < o) s[threadIdx.x] += s[threadIdx.x + o];
        __syncthreads();
    }
    if (threadIdx.x == 0) bs[blockIdx.x] = s[0];
}

template<int NSX, int VPTX>
__global__ void ks2(int* __restrict__ bs) {
    __shared__ int s[256];
    int t = threadIdx.x;
    int v[VPTX];
    int base = t * VPTX, sum = 0;
#pragma unroll
    for (int k = 0; k < VPTX; k++) {
        int idx = base + k;
        int x = (idx < NSX) ? bs[idx] : 0;
        v[k] = sum; sum += x;
    }
    s[t] = sum;
    __syncthreads();
    for (int o = 1; o < 256; o <<= 1) {
        int add = (t >= o) ? s[t - o] : 0;
        __syncthreads();
        s[t] += add;
        __syncthreads();
    }
    int excl = (t == 0) ? 0 : s[t - 1];
#pragma unroll
    for (int k = 0; k < VPTX; k++) {
        int idx = base + k;
        if (idx < NSX) bs[idx] = excl + v[k];
    }
}

__global__ void ks3(int* __restrict__ a, const int* __restrict__ bs, int* __restrict__ dup) {
    __shared__ int s[256];
    int t = threadIdx.x, i = blockIdx.x * 256 + t;
    int v = a[i];
    s[t] = v;
    __syncthreads();
    for (int o = 1; o < 256; o <<= 1) {
        int add = (t >= o) ? s[t - o] : 0;
        __syncthreads();
        s[t] += add;
        __syncthreads();
    }
    int val = s[t] - v + bs[blockIdx.x];
    a[i] = val;
    if (dup != nullptr) dup[i] = val;
}

// ---------- phase B: per-block counting sort in LDS, then coalesced drain ----------
__global__ void __launch_bounds__(256) ksB(const int* __restrict__ ei, const float* __restrict__ ea,
                                           const int* __restrict__ cmat, float4* __restrict__ buf1) {
    __shared__ float4 rec[CHUNK];
    __shared__ unsigned short sbkt[CHUNK];
    __shared__ int lh[NBKT];
    __shared__ int lex[NBKT];
    __shared__ int gb[NBKT];
    __shared__ int sc[256];
    int t = threadIdx.x;
    int b0 = blockIdx.x * CHUNK;
    int nval = min(CHUNK, N_EDGES - b0);
    if (t < NBKT) lh[t] = 0;
    __syncthreads();
    for (int i = t; i < nval; i += 256)
        atomicAdd(&lh[ei[N_EDGES + b0 + i] >> 9], 1);
    __syncthreads();
    sc[t] = (t < NBKT) ? lh[t] : 0;
    __syncthreads();
    for (int o = 1; o < 256; o <<= 1) {
        int add = (t >= o) ? sc[t - o] : 0;
        __syncthreads();
        sc[t] += add;
        __syncthreads();
    }
    if (t < NBKT) {
        lex[t] = sc[t] - lh[t];
        gb[t] = cmat[t * NBLKA + blockIdx.x];
        lh[t] = sc[t] - lh[t];
    }
    __syncthreads();
    for (int i = t; i < nval; i += 256) {
        int e = b0 + i;
        int src = ei[e], dst = ei[N_EDGES + e];
        float a0 = ea[(size_t)e * 3 + 0], a1 = ea[(size_t)e * 3 + 1], a2 = ea[(size_t)e * 3 + 2];
        int bkt = dst >> 9;
        int r = atomicAdd(&lh[bkt], 1);
        rec[r] = make_float4(a0, a1, a2, __int_as_float(src | ((dst & 511) << 17)));
        sbkt[r] = (unsigned short)bkt;
    }
    __syncthreads();
    for (int p = t; p < nval; p += 256) {
        int bkt = sbkt[p];
        buf1[gb[bkt] + (p - lex[bkt])] = rec[p];
    }
}

// ---------- single-pass CSR placement: atomic rank cursors, 16 slices per bucket ----------
__global__ void __launch_bounds__(256) k_place(const int* __restrict__ cmat,
                                               const float4* __restrict__ buf1,
                                               int* __restrict__ cursor,
                                               float4* __restrict__ packed) {
    int g = blockIdx.x >> 4, sl = blockIdx.x & (PSLICE - 1);
    int bb = cmat[g * NBLKA];
    int be = (g == NBKT - 1) ? N_EDGES : cmat[(g + 1) * NBLKA];
    int len = be - bb;
    int ch = (len + PSLICE - 1) >> 4;
    int s0 = bb + sl * ch;
    int e0 = min(s0 + ch, be);
    for (int j = s0 + (int)threadIdx.x; j < e0; j += 256) {
        float4 r = buf1[j];
        int bits = __float_as_int(r.w);
        int nn = (g << 9) + (bits >> 17);
        int pos = atomicAdd(&cursor[nn], 1);
        packed[pos] = make_float4(r.x, r.y, r.z, __int_as_float(bits & 0x1FFFF));
    }
}

// ---------- pull aggregation: 32 threads/node, fp16 gather, unroll-4; writes zin = self + agg ----------
// BN=true: self-term applies relu(BN1(z)) inline (fp32, exact)
template<bool BN>
__global__ void __launch_bounds__(256) k_agg(const float4* __restrict__ packed,
                                             const int* __restrict__ offs,
                                             const float* __restrict__ eW, const float* __restrict__ eb,
                                             const __half* __restrict__ h16,
                                             const float* __restrict__ hs,
                                             const float* __restrict__ stats,
                                             const float* __restrict__ bng, const float* __restrict__ bnb,
                                             float* __restrict__ zin) {
    int t = blockIdx.x * 256 + threadIdx.x;   // N_NODES*32 exact
    int n = t >> 5, s = t & 31;
    int q = s & 7, part = s >> 3;
    int c0 = q * 4;
    float w0[4], w1[4], w2[4], bb4[4];
#pragma unroll
    for (int i = 0; i < 4; i++) {
        w0[i] = eW[c0 + i];
        w1[i] = eW[32 + c0 + i];
        w2[i] = eW[64 + c0 + i];
        bb4[i] = eb[c0 + i];
    }
    int beg = offs[n], end = offs[n + 1];
    float acc0[4] = {0.f, 0.f, 0.f, 0.f};
    float acc1[4] = {0.f, 0.f, 0.f, 0.f};
    int j = beg + part;
    for (; j + 12 < end; j += 16) {
        float4 pa = packed[j];
        float4 pb = packed[j + 4];
        float4 pc = packed[j + 8];
        float4 pd = packed[j + 12];
        float2 ra = *(const float2*)(h16 + (size_t)__float_as_int(pa.w) * 32 + c0);
        float2 rb = *(const float2*)(h16 + (size_t)__float_as_int(pb.w) * 32 + c0);
        float2 rc = *(const float2*)(h16 + (size_t)__float_as_int(pc.w) * 32 + c0);
        float2 rd = *(const float2*)(h16 + (size_t)__float_as_int(pd.w) * 32 + c0);
        float2 a01 = __half22float2(*(__half2*)&ra.x);
        float2 a23 = __half22float2(*(__half2*)&ra.y);
        float2 b01 = __half22float2(*(__half2*)&rb.x);
        float2 b23 = __half22float2(*(__half2*)&rb.y);
        float2 c01 = __half22float2(*(__half2*)&rc.x);
        float2 c23 = __half22float2(*(__half2*)&rc.y);
        float2 d01 = __half22float2(*(__half2*)&rd.x);
        float2 d23 = __half22float2(*(__half2*)&rd.y);
        float ha4[4] = {a01.x, a01.y, a23.x, a23.y};
        float hb4[4] = {b01.x, b01.y, b23.x, b23.y};
        float hc4[4] = {c01.x, c01.y, c23.x, c23.y};
        float hd4[4] = {d01.x, d01.y, d23.x, d23.y};
#pragma unroll
        for (int i = 0; i < 4; i++) {
            acc0[i] += fmaxf(ha4[i] + pa.x * w0[i] + pa.y * w1[i] + pa.z * w2[i] + bb4[i], 0.f);
            acc1[i] += fmaxf(hb4[i] + pb.x * w0[i] + pb.y * w1[i] + pb.z * w2[i] + bb4[i], 0.f);
            acc0[i] += fmaxf(hc4[i] + pc.x * w0[i] + pc.y * w1[i] + pc.z * w2[i] + bb4[i], 0.f);
            acc1[i] += fmaxf(hd4[i] + pd.x * w0[i] + pd.y * w1[i] + pd.z * w2[i] + bb4[i], 0.f);
        }
    }
    for (; j < end; j += 4) {
        float4 p = packed[j];
        float2 r = *(const float2*)(h16 + (size_t)__float_as_int(p.w) * 32 + c0);
        float2 a01 = __half22float2(*(__half2*)&r.x);
        float2 a23 = __half22float2(*(__half2*)&r.y);
        float hp4[4] = {a01.x, a01.y, a23.x, a23.y};
#pragma unroll
        for (int i = 0; i < 4; i++)
            acc0[i] += fmaxf(hp4[i] + p.x * w0[i] + p.y * w1[i] + p.z * w2[i] + bb4[i], 0.f);
    }
    float acc[4];
#pragma unroll
    for (int i = 0; i < 4; i++) {
        acc[i] = acc0[i] + acc1[i];
        acc[i] += __shfl_xor(acc[i], 8, 64);
        acc[i] += __shfl_xor(acc[i], 16, 64);
    }
    if (part == 0) {
        float4 hq = *(const float4*)(hs + (size_t)n * 32 + c0);   // coalesced, L2-warm
        float* hp = (float*)&hq;
        float sv[4];
        if (BN) {
            const float invN = 1.0f / (float)N_NODES;
#pragma unroll
            for (int i = 0; i < 4; i++) {
                int c = c0 + i;
                float mu = stats[c] * invN;
                float var = stats[32 + c] * invN - mu * mu;
                float scl = bng[c] / sqrtf(var + BN_EPS);
                float sft = bnb[c] - mu * scl;
                sv[i] = fmaxf(hp[i] * scl + sft, 0.f);
            }
        } else {
#pragma unroll
            for (int i = 0; i < 4; i++) sv[i] = hp[i];
        }
        *(float4*)(zin + (size_t)n * 32 + c0) =
            make_float4(acc[0] + sv[0], acc[1] + sv[1], acc[2] + sv[2], acc[3] + sv[3]);
    }
}

// ---------- fused MLP + BN stats: z = relu(zin@W1+b1)@W2+b2, stats += {sum, sumsq} ----------
__global__ void __launch_bounds__(256, 4) k_mlp(float* __restrict__ zio,
                                                const float* __restrict__ W1, const float* __restrict__ B1,
                                                const float* __restrict__ W2, const float* __restrict__ b2,
                                                float* __restrict__ stats) {
    __shared__ float sW1[HPAD * W1S];  // stride 36 (2-way bank alias = free)
    __shared__ float sW2[2560];
    __shared__ float sB1[80];
    __shared__ float sb2[32];
    __shared__ float hidL[32 * 84];
    __shared__ float lsum[128];
    __shared__ float lsq[128];
    for (int i = threadIdx.x; i < 2560; i += 256) {
        int j = i >> 5, c = i & 31;
        sW1[j * W1S + c] = W1[i];
        sW2[i] = W2[i];
    }
    if (threadIdx.x < 80) sB1[threadIdx.x] = B1[threadIdx.x];
    if (threadIdx.x < 32) sb2[threadIdx.x] = b2[threadIdx.x];
    __syncthreads();
    unsigned t = blockIdx.x * 256 + threadIdx.x;
    unsigned lane = threadIdx.x & 63;
    unsigned wv = threadIdx.x >> 6;
    unsigned oct = lane >> 3;
    unsigned nd = lane & 7;
    unsigned n = (t >> 6) * 8 + nd;
    const float4* ap = (const float4*)(zio + (size_t)n * 32);
    float zc[32];
#pragma unroll
    for (int q = 0; q < 8; q++) {
        float4 av = ap[q];
        zc[q * 4 + 0] = av.x;
        zc[q * 4 + 1] = av.y;
        zc[q * 4 + 2] = av.z;
        zc[q * 4 + 3] = av.w;
    }
    float hid[10];
#pragma unroll
    for (int i = 0; i < 10; i++) {
        int j = (int)oct * 10 + i;
        const float4* wp = (const float4*)(sW1 + j * W1S);
        float a0 = 0.f, a1 = 0.f, a2 = 0.f, a3 = 0.f;
#pragma unroll
        for (int q = 0; q < 8; q++) {
            float4 wv4 = wp[q];
            a0 += zc[q * 4 + 0] * wv4.x;
            a1 += zc[q * 4 + 1] * wv4.y;
            a2 += zc[q * 4 + 2] * wv4.z;
            a3 += zc[q * 4 + 3] * wv4.w;
        }
        hid[i] = fmaxf(sB1[j] + ((a0 + a1) + (a2 + a3)), 0.f);
    }
    float* hrow = &hidL[(wv * 8 + nd) * 84];
#pragma unroll
    for (int i = 0; i < 10; i++) hrow[oct * 10 + i] = hid[i];
    float4 zo = *(const float4*)(sb2 + oct * 4);
    const float4* hv4 = (const float4*)hrow;
#pragma unroll
    for (int k = 0; k < 20; k++) {
        float4 hv = hv4[k];
        const float* wr = sW2 + (k * 4) * 32 + oct * 4;
        float4 wa = *(const float4*)(wr);
        float4 wb = *(const float4*)(wr + 32);
        float4 wc = *(const float4*)(wr + 64);
        float4 wd = *(const float4*)(wr + 96);
        zo.x += hv.x * wa.x + hv.y * wb.x + hv.z * wc.x + hv.w * wd.x;
        zo.y += hv.x * wa.y + hv.y * wb.y + hv.z * wc.y + hv.w * wd.y;
        zo.z += hv.x * wa.z + hv.y * wb.z + hv.z * wc.z + hv.w * wd.z;
        zo.w += hv.x * wa.w + hv.y * wb.w + hv.z * wc.w + hv.w * wd.w;
    }
    *(float4*)(zio + (size_t)n * 32 + oct * 4) = zo;
    // ---- fused BN stats: reduce over the 8 nodes (nd) in each oct group ----
    float s0 = zo.x, s1 = zo.y, s2 = zo.z, s3 = zo.w;
    float q0 = zo.x * zo.x, q1 = zo.y * zo.y, q2 = zo.z * zo.z, q3 = zo.w * zo.w;
#pragma unroll
    for (int m = 1; m < 8; m <<= 1) {
        s0 += __shfl_xor(s0, m, 64); s1 += __shfl_xor(s1, m, 64);
        s2 += __shfl_xor(s2, m, 64); s3 += __shfl_xor(s3, m, 64);
        q0 += __shfl_xor(q0, m, 64); q1 += __shfl_xor(q1, m, 64);
        q2 += __shfl_xor(q2, m, 64); q3 += __shfl_xor(q3, m, 64);
    }
    if (nd == 0) {
        int base = wv * 32 + oct * 4;
        lsum[base + 0] = s0; lsum[base + 1] = s1; lsum[base + 2] = s2; lsum[base + 3] = s3;
        lsq[base + 0] = q0;  lsq[base + 1] = q1;  lsq[base + 2] = q2;  lsq[base + 3] = q3;
    }
    __syncthreads();
    if (threadIdx.x < 32) {
        int c = threadIdx.x;
        float tot = lsum[c] + lsum[32 + c] + lsum[64 + c] + lsum[96 + c];
        atomicAdd(&stats[c], tot);
    } else if (threadIdx.x < 64) {
        int c = threadIdx.x - 32;
        float tot = lsq[c] + lsq[32 + c] + lsq[64 + c] + lsq[96 + c];
        atomicAdd(&stats[32 + c], tot);
    }
}

// ---------- BN apply + relu, fp16 mirror only (layer-1) ----------
__global__ void k_bnh(const float* __restrict__ z, __half* __restrict__ m,
                      const float* __restrict__ stats, const float* __restrict__ g,
                      const float* __restrict__ b) {
    int t = blockIdx.x * 256 + threadIdx.x;
    if (t >= N_NODES * 8) return;
    int q = t & 7;
    float4 zv = ((const float4*)z)[t];
    float* zp = (float*)&zv;
    float ov[4];
    const float invN = 1.0f / (float)N_NODES;
#pragma unroll
    for (int i = 0; i < 4; i++) {
        int c = q * 4 + i;
        float mu = stats[c] * invN;
        float var = stats[32 + c] * invN - mu * mu;
        float sc = g[c] / sqrtf(var + BN_EPS);
        ov[i] = fmaxf((zp[i] - mu) * sc + b[c], 0.f);
    }
    __half2* hq = (__half2*)(m + (size_t)t * 4);
    hq[0] = __floats2half2_rn(ov[0], ov[1]);
    hq[1] = __floats2half2_rn(ov[2], ov[3]);
}

// ---------- graph offsets (batch is sorted) ----------
__global__ void k_goff(const int* __restrict__ batch, int* __restrict__ goff) {
    int g = blockIdx.x * 256 + threadIdx.x;
    if (g > N_GRAPHS) return;
    int lo = 0, hi = N_NODES;
    while (lo < hi) {
        int mid = (lo + hi) >> 1;
        if (batch[mid] < g) lo = mid + 1; else hi = mid;
    }
    goff[g] = lo;
}

// ---------- mean-pool with fused BN2+relu: one wave per graph ----------
__global__ void __launch_bounds__(256) k_pool2(const float* __restrict__ z, const int* __restrict__ goff,
                                               const float* __restrict__ stats,
                                               const float* __restrict__ g, const float* __restrict__ b,
                                               float* __restrict__ gsum) {
    int wid = threadIdx.x >> 6, lane = threadIdx.x & 63;
    int gi = blockIdx.x * 4 + wid;
    if (gi >= N_GRAPHS) return;
    int s = goff[gi], e = goff[gi + 1];
    int c = lane & 31, half = lane >> 5;
    const float invN = 1.0f / (float)N_NODES;
    float mu = stats[c] * invN;
    float var = stats[32 + c] * invN - mu * mu;
    float scl = g[c] / sqrtf(var + BN_EPS);
    float sft = b[c] - mu * scl;
    float acc = 0.f;
    for (int n = s + half; n < e; n += 2)
        acc += fmaxf(z[(size_t)n * 32 + c] * scl + sft, 0.f);
    acc += __shfl_down(acc, 32, 64);
    if (lane < 32) gsum[(size_t)gi * 32 + c] = acc;
}

__global__ void k_head(const float* __restrict__ gsum, const int* __restrict__ goff,
                       const float* __restrict__ W1, const float* __restrict__ b1,
                       const float* __restrict__ W2, const float* __restrict__ b2,
                       float* __restrict__ out) {
    __shared__ float sW1[512], sb1[16], sW2[32], sb2[2];
    for (int i = threadIdx.x; i < 512; i += 256) sW1[i] = W1[i];
    if (threadIdx.x < 16) sb1[threadIdx.x] = b1[threadIdx.x];
    if (threadIdx.x < 32) sW2[threadIdx.x] = W2[threadIdx.x];
    if (threadIdx.x < 2) sb2[threadIdx.x] = b2[threadIdx.x];
    __syncthreads();
    int gI = blockIdx.x * 256 + threadIdx.x;
    if (gI >= N_GRAPHS) return;
    float cnt = (float)(goff[gI + 1] - goff[gI]);
    float inv = 1.0f / fmaxf(cnt, 1.0f);
    float gx[32];
#pragma unroll
    for (int c = 0; c < 32; c++) gx[c] = gsum[(size_t)gI * 32 + c] * inv;
    float hid[16];
#pragma unroll
    for (int j = 0; j < 16; j++) {
        float a = sb1[j];
#pragma unroll
        for (int c = 0; c < 32; c++) a += gx[c] * sW1[c * 16 + j];
        hid[j] = fmaxf(a, 0.f);
    }
#pragma unroll
    for (int o = 0; o < 2; o++) {
        float a = sb2[o];
#pragma unroll
        for (int j = 0; j < 16; j++) a += hid[j] * sW2[j * 2 + o];
        out[(size_t)gI * 2 + o] = a;
    }
}

extern "C" void kernel_launch(void* const* d_in, const int* in_sizes, int n_in,
                              void* d_out, int out_size, void* d_ws, size_t ws_size,
                              hipStream_t stream) {
    const float* x       = (const float*)d_in[0];
    const int*   ei      = (const int*)d_in[1];
    const float* eattr   = (const float*)d_in[2];
    const int*   batch   = (const int*)d_in[3];
    const float* node_w  = (const float*)d_in[4];
    const float* node_b  = (const float*)d_in[5];
    const float* edge_w  = (const float*)d_in[6];
    const float* edge_b  = (const float*)d_in[7];
    const float* conv_w1 = (const float*)d_in[8];
    const float* conv_b1 = (const float*)d_in[9];
    const float* conv_w2 = (const float*)d_in[10];
    const float* conv_b2 = (const float*)d_in[11];
    const float* bn_g    = (const float*)d_in[12];
    const float* bn_b    = (const float*)d_in[13];
    const float* lin1_w  = (const float*)d_in[14];
    const float* lin1_b  = (const float*)d_in[15];
    const float* lin2_w  = (const float*)d_in[16];
    const float* lin2_b  = (const float*)d_in[17];
    float* out = (float*)d_out;

    float4* buf1    = (float4*)d_ws;                        // 51.2 MB
    float4* packed  = buf1 + N_EDGES;                       // 51.2 MB
    float*  h       = (float*)(packed + N_EDGES);           // 12.8 MB (h0, then zin2/z2)
    float*  agg     = h + (size_t)N_NODES * 32;             // 12.8 MB (zin1/z1)
    __half* m16     = (__half*)(agg + (size_t)N_NODES * 32);// 6.4 MB (h0 mirror, then BN1 mirror)
    int*    cmat    = (int*)(m16 + (size_t)N_NODES * 32);   // LALLOC ints  -- memset zone start
    int*    nodeCnt = cmat + LALLOC;                        // NPAD2 ints (becomes offs after scan)
    float*  stats   = (float*)(nodeCnt + NPAD2);            // 128 floats (2 layers) -- memset zone end
    int*    cursor  = (int*)(stats + 128);                  // NPAD2 ints
    int*    t1      = cursor + NPAD2;                       // 1280
    int*    t2      = t1 + 1280;                            // 512
    int*    goff    = t2 + 512;                             // N_GRAPHS+1
    float*  gsum    = (float*)(goff + N_GRAPHS + 1);        // G*32
    float*  w1tp    = gsum + (size_t)N_GRAPHS * 32;         // 2*80*32
    float*  b1p     = w1tp + 2 * HPAD * 32;                 // 2*80
    float*  w2p     = b1p + 2 * HPAD;                       // 2*80*32

    int nb_nodes = (N_NODES + 255) / 256;
    int nb_vec   = (N_NODES * 8 + 255) / 256;

    hipMemsetAsync(cmat, 0, (size_t)(LALLOC + NPAD2 + 128) * sizeof(int), stream);
    k_encode<<<nb_nodes, 256, 0, stream>>>(x, node_w, node_b, h, m16);
    k_prep<<<(2 * HPAD * 32 + 2 * HPAD + 255) / 256, 256, 0, stream>>>(
        conv_w1, conv_b1, conv_w2, w1tp, b1p, w2p);
    k_goff<<<(N_GRAPHS + 1 + 255) / 256, 256, 0, stream>>>(batch, goff);

    ksA<<<NBLKA, 256, 0, stream>>>(ei, cmat, nodeCnt);
    // scan A: cmat (bucket x chunk matrix) -> bucket-contiguous bases
    ks1<<<NS1, 256, 0, stream>>>(cmat, t1);
    ks2<NS1, 5><<<1, 256, 0, stream>>>(t1);
    ks3<<<NS1, 256, 0, stream>>>(cmat, t1, nullptr);
    // scan B: nodeCnt -> CSR offs (dup into cursor for atomic ranks)
    ks1<<<NSB, 256, 0, stream>>>(nodeCnt, t2);
    ks2<NSB, 2><<<1, 256, 0, stream>>>(t2);
    ks3<<<NSB, 256, 0, stream>>>(nodeCnt, t2, cursor);

    ksB<<<NBLKA, 256, 0, stream>>>(ei, eattr, cmat, buf1);
    k_place<<<NBKT * PSLICE, 256, 0, stream>>>(cmat, buf1, cursor, packed);

    // layer 1: agg(h0) -> zin1(agg) -> mlp -> z1(agg) + stats[0:64] -> BN mirror m16
    k_agg<false><<<N_NODES * 32 / 256, 256, 0, stream>>>(packed, nodeCnt, edge_w, edge_b,
                                                         m16, h, stats, bn_g, bn_b, agg);
    k_mlp<<<N_NODES * 8 / 256, 256, 0, stream>>>(agg, w1tp, b1p, w2p, conv_b2, stats);
    k_bnh<<<nb_vec, 256, 0, stream>>>(agg, m16, stats, bn_g, bn_b);
    // layer 2: agg gathers BN1 mirror, self-term = relu(BN1(z1)) inline -> zin2(h) -> mlp -> z2(h) + stats[64:]
    k_agg<true><<<N_NODES * 32 / 256, 256, 0, stream>>>(packed, nodeCnt, edge_w, edge_b,
                                                        m16, agg, stats, bn_g, bn_b, h);
    k_mlp<<<N_NODES * 8 / 256, 256, 0, stream>>>(h, w1tp + HPAD * 32, b1p + HPAD,
                                                 w2p + HPAD * 32, conv_b2 + 32, stats + 64);
    // pool applies BN2+relu inline from z2
    k_pool2<<<(N_GRAPHS + 3) / 4, 256, 0, stream>>>(h, goff, stats + 64, bn_g + 32, bn_b + 32, gsum);
    k_head<<<(N_GRAPHS + 255) / 256, 256, 0, stream>>>(gsum, goff, lin1_w, lin1_b, lin2_w, lin2_b, out);
}

// Round 3
// 582.302 us; speedup vs baseline: 2.8984x; 1.2818x over previous
//
#include <hip/hip_runtime.h>
#include <hip/hip_fp16.h>

#define N_NODES 100000
#define N_EDGES 3200000
#define N_GRAPHS 5000
#define BN_EPS 1e-5f
#define HPAD 80        // hidden 75 padded to 80
#define CHUNK 2048     // edges per bucket-sort block
#define NBLKA 1563     // ceil(N_EDGES / CHUNK)
#define NBKT 392       // buckets of 256 nodes (dst >> 8)
#define NPAD2 (NBKT * 256)     // 100352
#define NBLK_TOT (NBKT * NBLKA)  // 612696
#define NS1 2394       // ceil(NBLK_TOT / 256)
#define LALLOC (NS1 * 256)
#define W1S 36         // sW1 row stride: 2-way bank alias only (free)

// ---------- node encoder: h = x @ node_w + node_b (fp32 + fp16 mirror) ----------
__global__ void k_encode(const float* __restrict__ x, const float* __restrict__ W,
                         const float* __restrict__ b, float* __restrict__ h,
                         __half* __restrict__ h16) {
    __shared__ float sW[448];
    __shared__ float sb[32];
    for (int i = threadIdx.x; i < 448; i += 256) sW[i] = W[i];
    if (threadIdx.x < 32) sb[threadIdx.x] = b[threadIdx.x];
    __syncthreads();
    int n = blockIdx.x * 256 + threadIdx.x;
    if (n >= N_NODES) return;
    float xi[14];
#pragma unroll
    for (int k = 0; k < 14; k++) xi[k] = x[n * 14 + k];
    float4* hp = (float4*)(h + (size_t)n * 32);
    __half2* hq = (__half2*)(h16 + (size_t)n * 32);
#pragma unroll
    for (int q = 0; q < 8; q++) {
        float4 acc;
        float* ap = (float*)&acc;
#pragma unroll
        for (int i = 0; i < 4; i++) {
            int c = q * 4 + i;
            float a = sb[c];
#pragma unroll
            for (int k = 0; k < 14; k++) a += xi[k] * sW[k * 32 + c];
            ap[i] = a;
        }
        hp[q] = acc;
        hq[q * 2 + 0] = __floats2half2_rn(acc.x, acc.y);
        hq[q * 2 + 1] = __floats2half2_rn(acc.z, acc.w);
    }
}

// ---------- weight prep ----------
__global__ void k_prep(const float* __restrict__ W1, const float* __restrict__ b1,
                       const float* __restrict__ W2,
                       float* __restrict__ w1tp, float* __restrict__ b1p,
                       float* __restrict__ w2p) {
    int i = blockIdx.x * 256 + threadIdx.x;
    if (i < 2 * HPAD * 32) {
        int l = i / (HPAD * 32), r = i % (HPAD * 32);
        int j = r / 32, c = r % 32;
        w1tp[i] = (j < 75) ? W1[l * 2400 + c * 75 + j] : 0.f;
        w2p[i]  = (j < 75) ? W2[l * 2400 + j * 32 + c] : 0.f;
    } else if (i < 2 * HPAD * 32 + 2 * HPAD) {
        int k = i - 2 * HPAD * 32;
        int l = k / HPAD, j = k % HPAD;
        b1p[k] = (j < 75) ? b1[l * 75 + j] : 0.f;
    }
}

// ---------- bucket sort phase A: per-chunk histogram (LDS atomics only) ----------
__global__ void __launch_bounds__(256) ksA(const int* __restrict__ ei, int* __restrict__ cmat) {
    __shared__ int lh[NBKT];
    for (int i = threadIdx.x; i < NBKT; i += 256) lh[i] = 0;
    __syncthreads();
    int b0 = blockIdx.x * CHUNK;
    for (int i = threadIdx.x; i < CHUNK; i += 256) {
        int e = b0 + i;
        if (e < N_EDGES) atomicAdd(&lh[ei[N_EDGES + e] >> 8], 1);
    }
    __syncthreads();
    for (int i = threadIdx.x; i < NBKT; i += 256)
        cmat[i * NBLKA + blockIdx.x] = lh[i];
}

// ---------- 3-kernel exclusive scan of cmat ----------
__global__ void ks1(const int* __restrict__ a, int* __restrict__ bs) {
    __shared__ int s[256];
    int i = blockIdx.x * 256 + threadIdx.x;
    s[threadIdx.x] = a[i];
    __syncthreads();
    for (int o = 128; o > 0; o >>= 1) {
        if (threadIdx.x < o) s[threadIdx.x] += s[threadIdx.x + o];
        __syncthreads();
    }
    if (threadIdx.x == 0) bs[blockIdx.x] = s[0];
}

template<int NSX, int VPTX>
__global__ void ks2(int* __restrict__ bs) {
    __shared__ int s[256];
    int t = threadIdx.x;
    int v[VPTX];
    int base = t * VPTX, sum = 0;
#pragma unroll
    for (int k = 0; k < VPTX; k++) {
        int idx = base + k;
        int x = (idx < NSX) ? bs[idx] : 0;
        v[k] = sum; sum += x;
    }
    s[t] = sum;
    __syncthreads();
    for (int o = 1; o < 256; o <<= 1) {
        int add = (t >= o) ? s[t - o] : 0;
        __syncthreads();
        s[t] += add;
        __syncthreads();
    }
    int excl = (t == 0) ? 0 : s[t - 1];
#pragma unroll
    for (int k = 0; k < VPTX; k++) {
        int idx = base + k;
        if (idx < NSX) bs[idx] = excl + v[k];
    }
}

__global__ void ks3(int* __restrict__ a, const int* __restrict__ bs) {
    __shared__ int s[256];
    int t = threadIdx.x, i = blockIdx.x * 256 + t;
    int v = a[i];
    s[t] = v;
    __syncthreads();
    for (int o = 1; o < 256; o <<= 1) {
        int add = (t >= o) ? s[t - o] : 0;
        __syncthreads();
        s[t] += add;
        __syncthreads();
    }
    a[i] = s[t] - v + bs[blockIdx.x];
}

// ---------- phase B: per-block counting sort in LDS, then coalesced drain (+key bytes) ----------
__global__ void __launch_bounds__(256) ksB(const int* __restrict__ ei, const float* __restrict__ ea,
                                           const int* __restrict__ cmat, float4* __restrict__ buf1,
                                           unsigned char* __restrict__ key) {
    __shared__ float4 rec[CHUNK];          // 32 KB
    __shared__ unsigned short sbkt[CHUNK]; // 4 KB
    __shared__ int lh[NBKT];
    __shared__ int lex[NBKT];
    __shared__ int gb[NBKT];
    __shared__ int sc[256];
    int t = threadIdx.x;
    int b0 = blockIdx.x * CHUNK;
    int nval = min(CHUNK, N_EDGES - b0);
    for (int i = t; i < NBKT; i += 256) lh[i] = 0;
    __syncthreads();
    for (int i = t; i < nval; i += 256)
        atomicAdd(&lh[ei[N_EDGES + b0 + i] >> 8], 1);
    __syncthreads();
    // scan 392 buckets: 2 per thread + 256-wide scan of thread totals
    int x0 = (t * 2 < NBKT) ? lh[t * 2] : 0;
    int x1 = (t * 2 + 1 < NBKT) ? lh[t * 2 + 1] : 0;
    int v0 = 0, v1 = x0, run = x0 + x1;
    sc[t] = run;
    __syncthreads();
    for (int o = 1; o < 256; o <<= 1) {
        int add = (t >= o) ? sc[t - o] : 0;
        __syncthreads();
        sc[t] += add;
        __syncthreads();
    }
    int excl = (t == 0) ? 0 : sc[t - 1];
    if (t * 2 < NBKT) {
        int base = excl + v0;
        lex[t * 2] = base; lh[t * 2] = base;
        gb[t * 2] = cmat[(t * 2) * NBLKA + blockIdx.x];
    }
    if (t * 2 + 1 < NBKT) {
        int base = excl + v1;
        lex[t * 2 + 1] = base; lh[t * 2 + 1] = base;
        gb[t * 2 + 1] = cmat[(t * 2 + 1) * NBLKA + blockIdx.x];
    }
    __syncthreads();
    for (int i = t; i < nval; i += 256) {
        int e = b0 + i;
        int src = ei[e], dst = ei[N_EDGES + e];
        float a0 = ea[(size_t)e * 3 + 0], a1 = ea[(size_t)e * 3 + 1], a2 = ea[(size_t)e * 3 + 2];
        int bkt = dst >> 8;
        int r = atomicAdd(&lh[bkt], 1);
        rec[r] = make_float4(a0, a1, a2, __int_as_float(src | ((dst & 255) << 17)));
        sbkt[r] = (unsigned short)bkt;
    }
    __syncthreads();
    for (int p = t; p < nval; p += 256) {
        int bkt = sbkt[p];
        int gp = gb[bkt] + (p - lex[bkt]);
        float4 r = rec[p];
        buf1[gp] = r;
        key[gp] = (unsigned char)(((unsigned)__float_as_int(r.w)) >> 17);
    }
}

// ---------- phase C: per-256-node-bucket exact CSR (LDS atomics, byte-key count pass) ----------
__global__ void __launch_bounds__(512) ksC(const int* __restrict__ cmat, const float4* __restrict__ buf1,
                                           const unsigned char* __restrict__ key,
                                           float4* __restrict__ packed, int* __restrict__ offs) {
    __shared__ int cnt[256];
    __shared__ int sc2[256];
    __shared__ int excl[256];
    int g = blockIdx.x, t = threadIdx.x;
    int bb = cmat[g * NBLKA];
    int be = (g == NBKT - 1) ? N_EDGES : cmat[(g + 1) * NBLKA];
    if (t < 256) cnt[t] = 0;
    __syncthreads();
    for (int j = bb + t; j < be; j += 512) atomicAdd(&cnt[key[j]], 1);
    __syncthreads();
    if (t < 256) sc2[t] = cnt[t];
    __syncthreads();
    for (int o = 1; o < 256; o <<= 1) {
        int add = 0;
        if (t < 256 && t >= o) add = sc2[t - o];
        __syncthreads();
        if (t < 256) sc2[t] += add;
        __syncthreads();
    }
    if (t < 256) {
        excl[t] = sc2[t] - cnt[t];
        offs[(g << 8) + t] = bb + excl[t];
        cnt[t] = 0;
    }
    if (g == NBKT - 1 && t == 0) offs[NPAD2] = N_EDGES;
    __syncthreads();
    for (int j = bb + t; j < be; j += 512) {
        float4 r = buf1[j];
        int bits = __float_as_int(r.w);
        int dl = bits >> 17;
        int rank = atomicAdd(&cnt[dl], 1);
        packed[bb + excl[dl] + rank] = make_float4(r.x, r.y, r.z, __int_as_float(bits & 0x1FFFF));
    }
}

// ---------- pull aggregation: 32 threads/node, fp16 gather, unroll-4; writes zin = self + agg ----------
// BN=true: self-term applies relu(BN1(z)) inline (fp32, exact)
template<bool BN>
__global__ void __launch_bounds__(256) k_agg(const float4* __restrict__ packed,
                                             const int* __restrict__ offs,
                                             const float* __restrict__ eW, const float* __restrict__ eb,
                                             const __half* __restrict__ h16,
                                             const float* __restrict__ hs,
                                             const float* __restrict__ stats,
                                             const float* __restrict__ bng, const float* __restrict__ bnb,
                                             float* __restrict__ zin) {
    int t = blockIdx.x * 256 + threadIdx.x;   // N_NODES*32 exact
    int n = t >> 5, s = t & 31;
    int q = s & 7, part = s >> 3;
    int c0 = q * 4;
    float w0[4], w1[4], w2[4], bb4[4];
#pragma unroll
    for (int i = 0; i < 4; i++) {
        w0[i] = eW[c0 + i];
        w1[i] = eW[32 + c0 + i];
        w2[i] = eW[64 + c0 + i];
        bb4[i] = eb[c0 + i];
    }
    int beg = offs[n], end = offs[n + 1];
    float acc0[4] = {0.f, 0.f, 0.f, 0.f};
    float acc1[4] = {0.f, 0.f, 0.f, 0.f};
    int j = beg + part;
    for (; j + 12 < end; j += 16) {
        float4 pa = packed[j];
        float4 pb = packed[j + 4];
        float4 pc = packed[j + 8];
        float4 pd = packed[j + 12];
        float2 ra = *(const float2*)(h16 + (size_t)__float_as_int(pa.w) * 32 + c0);
        float2 rb = *(const float2*)(h16 + (size_t)__float_as_int(pb.w) * 32 + c0);
        float2 rc = *(const float2*)(h16 + (size_t)__float_as_int(pc.w) * 32 + c0);
        float2 rd = *(const float2*)(h16 + (size_t)__float_as_int(pd.w) * 32 + c0);
        float2 a01 = __half22float2(*(__half2*)&ra.x);
        float2 a23 = __half22float2(*(__half2*)&ra.y);
        float2 b01 = __half22float2(*(__half2*)&rb.x);
        float2 b23 = __half22float2(*(__half2*)&rb.y);
        float2 c01 = __half22float2(*(__half2*)&rc.x);
        float2 c23 = __half22float2(*(__half2*)&rc.y);
        float2 d01 = __half22float2(*(__half2*)&rd.x);
        float2 d23 = __half22float2(*(__half2*)&rd.y);
        float ha4[4] = {a01.x, a01.y, a23.x, a23.y};
        float hb4[4] = {b01.x, b01.y, b23.x, b23.y};
        float hc4[4] = {c01.x, c01.y, c23.x, c23.y};
        float hd4[4] = {d01.x, d01.y, d23.x, d23.y};
#pragma unroll
        for (int i = 0; i < 4; i++) {
            acc0[i] += fmaxf(ha4[i] + pa.x * w0[i] + pa.y * w1[i] + pa.z * w2[i] + bb4[i], 0.f);
            acc1[i] += fmaxf(hb4[i] + pb.x * w0[i] + pb.y * w1[i] + pb.z * w2[i] + bb4[i], 0.f);
            acc0[i] += fmaxf(hc4[i] + pc.x * w0[i] + pc.y * w1[i] + pc.z * w2[i] + bb4[i], 0.f);
            acc1[i] += fmaxf(hd4[i] + pd.x * w0[i] + pd.y * w1[i] + pd.z * w2[i] + bb4[i], 0.f);
        }
    }
    for (; j < end; j += 4) {
        float4 p = packed[j];
        float2 r = *(const float2*)(h16 + (size_t)__float_as_int(p.w) * 32 + c0);
        float2 a01 = __half22float2(*(__half2*)&r.x);
        float2 a23 = __half22float2(*(__half2*)&r.y);
        float hp4[4] = {a01.x, a01.y, a23.x, a23.y};
#pragma unroll
        for (int i = 0; i < 4; i++)
            acc0[i] += fmaxf(hp4[i] + p.x * w0[i] + p.y * w1[i] + p.z * w2[i] + bb4[i], 0.f);
    }
    float acc[4];
#pragma unroll
    for (int i = 0; i < 4; i++) {
        acc[i] = acc0[i] + acc1[i];
        acc[i] += __shfl_xor(acc[i], 8, 64);
        acc[i] += __shfl_xor(acc[i], 16, 64);
    }
    if (part == 0) {
        float4 hq = *(const float4*)(hs + (size_t)n * 32 + c0);   // coalesced, L2-warm
        float* hp = (float*)&hq;
        float sv[4];
        if (BN) {
            const float invN = 1.0f / (float)N_NODES;
#pragma unroll
            for (int i = 0; i < 4; i++) {
                int c = c0 + i;
                float mu = stats[c] * invN;
                float var = stats[32 + c] * invN - mu * mu;
                float scl = bng[c] / sqrtf(var + BN_EPS);
                float sft = bnb[c] - mu * scl;
                sv[i] = fmaxf(hp[i] * scl + sft, 0.f);
            }
        } else {
#pragma unroll
            for (int i = 0; i < 4; i++) sv[i] = hp[i];
        }
        *(float4*)(zin + (size_t)n * 32 + c0) =
            make_float4(acc[0] + sv[0], acc[1] + sv[1], acc[2] + sv[2], acc[3] + sv[3]);
    }
}

// ---------- fused MLP + BN stats: z = relu(zin@W1+b1)@W2+b2, stats += {sum, sumsq} ----------
__global__ void __launch_bounds__(256, 4) k_mlp(float* __restrict__ zio,
                                                const float* __restrict__ W1, const float* __restrict__ B1,
                                                const float* __restrict__ W2, const float* __restrict__ b2,
                                                float* __restrict__ stats) {
    __shared__ float sW1[HPAD * W1S];  // stride 36 (2-way bank alias = free)
    __shared__ float sW2[2560];
    __shared__ float sB1[80];
    __shared__ float sb2[32];
    __shared__ float hidL[32 * 84];
    __shared__ float lsum[128];
    __shared__ float lsq[128];
    for (int i = threadIdx.x; i < 2560; i += 256) {
        int j = i >> 5, c = i & 31;
        sW1[j * W1S + c] = W1[i];
        sW2[i] = W2[i];
    }
    if (threadIdx.x < 80) sB1[threadIdx.x] = B1[threadIdx.x];
    if (threadIdx.x < 32) sb2[threadIdx.x] = b2[threadIdx.x];
    __syncthreads();
    unsigned t = blockIdx.x * 256 + threadIdx.x;
    unsigned lane = threadIdx.x & 63;
    unsigned wv = threadIdx.x >> 6;
    unsigned oct = lane >> 3;
    unsigned nd = lane & 7;
    unsigned n = (t >> 6) * 8 + nd;
    const float4* ap = (const float4*)(zio + (size_t)n * 32);
    float zc[32];
#pragma unroll
    for (int q = 0; q < 8; q++) {
        float4 av = ap[q];
        zc[q * 4 + 0] = av.x;
        zc[q * 4 + 1] = av.y;
        zc[q * 4 + 2] = av.z;
        zc[q * 4 + 3] = av.w;
    }
    float hid[10];
#pragma unroll
    for (int i = 0; i < 10; i++) {
        int j = (int)oct * 10 + i;
        const float4* wp = (const float4*)(sW1 + j * W1S);
        float a0 = 0.f, a1 = 0.f, a2 = 0.f, a3 = 0.f;
#pragma unroll
        for (int q = 0; q < 8; q++) {
            float4 wv4 = wp[q];
            a0 += zc[q * 4 + 0] * wv4.x;
            a1 += zc[q * 4 + 1] * wv4.y;
            a2 += zc[q * 4 + 2] * wv4.z;
            a3 += zc[q * 4 + 3] * wv4.w;
        }
        hid[i] = fmaxf(sB1[j] + ((a0 + a1) + (a2 + a3)), 0.f);
    }
    float* hrow = &hidL[(wv * 8 + nd) * 84];
#pragma unroll
    for (int i = 0; i < 10; i++) hrow[oct * 10 + i] = hid[i];
    float4 zo = *(const float4*)(sb2 + oct * 4);
    const float4* hv4 = (const float4*)hrow;
#pragma unroll
    for (int k = 0; k < 20; k++) {
        float4 hv = hv4[k];
        const float* wr = sW2 + (k * 4) * 32 + oct * 4;
        float4 wa = *(const float4*)(wr);
        float4 wb = *(const float4*)(wr + 32);
        float4 wc = *(const float4*)(wr + 64);
        float4 wd = *(const float4*)(wr + 96);
        zo.x += hv.x * wa.x + hv.y * wb.x + hv.z * wc.x + hv.w * wd.x;
        zo.y += hv.x * wa.y + hv.y * wb.y + hv.z * wc.y + hv.w * wd.y;
        zo.z += hv.x * wa.z + hv.y * wb.z + hv.z * wc.z + hv.w * wd.z;
        zo.w += hv.x * wa.w + hv.y * wb.w + hv.z * wc.w + hv.w * wd.w;
    }
    *(float4*)(zio + (size_t)n * 32 + oct * 4) = zo;
    // ---- fused BN stats: reduce over the 8 nodes (nd) in each oct group ----
    float s0 = zo.x, s1 = zo.y, s2 = zo.z, s3 = zo.w;
    float q0 = zo.x * zo.x, q1 = zo.y * zo.y, q2 = zo.z * zo.z, q3 = zo.w * zo.w;
#pragma unroll
    for (int m = 1; m < 8; m <<= 1) {
        s0 += __shfl_xor(s0, m, 64); s1 += __shfl_xor(s1, m, 64);
        s2 += __shfl_xor(s2, m, 64); s3 += __shfl_xor(s3, m, 64);
        q0 += __shfl_xor(q0, m, 64); q1 += __shfl_xor(q1, m, 64);
        q2 += __shfl_xor(q2, m, 64); q3 += __shfl_xor(q3, m, 64);
    }
    if (nd == 0) {
        int base = wv * 32 + oct * 4;
        lsum[base + 0] = s0; lsum[base + 1] = s1; lsum[base + 2] = s2; lsum[base + 3] = s3;
        lsq[base + 0] = q0;  lsq[base + 1] = q1;  lsq[base + 2] = q2;  lsq[base + 3] = q3;
    }
    __syncthreads();
    if (threadIdx.x < 32) {
        int c = threadIdx.x;
        float tot = lsum[c] + lsum[32 + c] + lsum[64 + c] + lsum[96 + c];
        atomicAdd(&stats[c], tot);
    } else if (threadIdx.x < 64) {
        int c = threadIdx.x - 32;
        float tot = lsq[c] + lsq[32 + c] + lsq[64 + c] + lsq[96 + c];
        atomicAdd(&stats[32 + c], tot);
    }
}

// ---------- BN apply + relu, fp16 mirror only (layer-1) ----------
__global__ void k_bnh(const float* __restrict__ z, __half* __restrict__ m,
                      const float* __restrict__ stats, const float* __restrict__ g,
                      const float* __restrict__ b) {
    int t = blockIdx.x * 256 + threadIdx.x;
    if (t >= N_NODES * 8) return;
    int q = t & 7;
    float4 zv = ((const float4*)z)[t];
    float* zp = (float*)&zv;
    float ov[4];
    const float invN = 1.0f / (float)N_NODES;
#pragma unroll
    for (int i = 0; i < 4; i++) {
        int c = q * 4 + i;
        float mu = stats[c] * invN;
        float var = stats[32 + c] * invN - mu * mu;
        float sc = g[c] / sqrtf(var + BN_EPS);
        ov[i] = fmaxf((zp[i] - mu) * sc + b[c], 0.f);
    }
    __half2* hq = (__half2*)(m + (size_t)t * 4);
    hq[0] = __floats2half2_rn(ov[0], ov[1]);
    hq[1] = __floats2half2_rn(ov[2], ov[3]);
}

// ---------- graph offsets (batch is sorted) ----------
__global__ void k_goff(const int* __restrict__ batch, int* __restrict__ goff) {
    int g = blockIdx.x * 256 + threadIdx.x;
    if (g > N_GRAPHS) return;
    int lo = 0, hi = N_NODES;
    while (lo < hi) {
        int mid = (lo + hi) >> 1;
        if (batch[mid] < g) lo = mid + 1; else hi = mid;
    }
    goff[g] = lo;
}

// ---------- mean-pool with fused BN2+relu: one wave per graph ----------
__global__ void __launch_bounds__(256) k_pool2(const float* __restrict__ z, const int* __restrict__ goff,
                                               const float* __restrict__ stats,
                                               const float* __restrict__ g, const float* __restrict__ b,
                                               float* __restrict__ gsum) {
    int wid = threadIdx.x >> 6, lane = threadIdx.x & 63;
    int gi = blockIdx.x * 4 + wid;
    if (gi >= N_GRAPHS) return;
    int s = goff[gi], e = goff[gi + 1];
    int c = lane & 31, half = lane >> 5;
    const float invN = 1.0f / (float)N_NODES;
    float mu = stats[c] * invN;
    float var = stats[32 + c] * invN - mu * mu;
    float scl = g[c] / sqrtf(var + BN_EPS);
    float sft = b[c] - mu * scl;
    float acc = 0.f;
    for (int n = s + half; n < e; n += 2)
        acc += fmaxf(z[(size_t)n * 32 + c] * scl + sft, 0.f);
    acc += __shfl_down(acc, 32, 64);
    if (lane < 32) gsum[(size_t)gi * 32 + c] = acc;
}

__global__ void k_head(const float* __restrict__ gsum, const int* __restrict__ goff,
                       const float* __restrict__ W1, const float* __restrict__ b1,
                       const float* __restrict__ W2, const float* __restrict__ b2,
                       float* __restrict__ out) {
    __shared__ float sW1[512], sb1[16], sW2[32], sb2[2];
    for (int i = threadIdx.x; i < 512; i += 256) sW1[i] = W1[i];
    if (threadIdx.x < 16) sb1[threadIdx.x] = b1[threadIdx.x];
    if (threadIdx.x < 32) sW2[threadIdx.x] = W2[threadIdx.x];
    if (threadIdx.x < 2) sb2[threadIdx.x] = b2[threadIdx.x];
    __syncthreads();
    int gI = blockIdx.x * 256 + threadIdx.x;
    if (gI >= N_GRAPHS) return;
    float cnt = (float)(goff[gI + 1] - goff[gI]);
    float inv = 1.0f / fmaxf(cnt, 1.0f);
    float gx[32];
#pragma unroll
    for (int c = 0; c < 32; c++) gx[c] = gsum[(size_t)gI * 32 + c] * inv;
    float hid[16];
#pragma unroll
    for (int j = 0; j < 16; j++) {
        float a = sb1[j];
#pragma unroll
        for (int c = 0; c < 32; c++) a += gx[c] * sW1[c * 16 + j];
        hid[j] = fmaxf(a, 0.f);
    }
#pragma unroll
    for (int o = 0; o < 2; o++) {
        float a = sb2[o];
#pragma unroll
        for (int j = 0; j < 16; j++) a += hid[j] * sW2[j * 2 + o];
        out[(size_t)gI * 2 + o] = a;
    }
}

extern "C" void kernel_launch(void* const* d_in, const int* in_sizes, int n_in,
                              void* d_out, int out_size, void* d_ws, size_t ws_size,
                              hipStream_t stream) {
    const float* x       = (const float*)d_in[0];
    const int*   ei      = (const int*)d_in[1];
    const float* eattr   = (const float*)d_in[2];
    const int*   batch   = (const int*)d_in[3];
    const float* node_w  = (const float*)d_in[4];
    const float* node_b  = (const float*)d_in[5];
    const float* edge_w  = (const float*)d_in[6];
    const float* edge_b  = (const float*)d_in[7];
    const float* conv_w1 = (const float*)d_in[8];
    const float* conv_b1 = (const float*)d_in[9];
    const float* conv_w2 = (const float*)d_in[10];
    const float* conv_b2 = (const float*)d_in[11];
    const float* bn_g    = (const float*)d_in[12];
    const float* bn_b    = (const float*)d_in[13];
    const float* lin1_w  = (const float*)d_in[14];
    const float* lin1_b  = (const float*)d_in[15];
    const float* lin2_w  = (const float*)d_in[16];
    const float* lin2_b  = (const float*)d_in[17];
    float* out = (float*)d_out;

    float4* buf1    = (float4*)d_ws;                        // 51.2 MB
    float4* packed  = buf1 + N_EDGES;                       // 51.2 MB
    float*  h       = (float*)(packed + N_EDGES);           // 12.8 MB (h0, then zin2/z2)
    float*  agg     = h + (size_t)N_NODES * 32;             // 12.8 MB (zin1/z1)
    __half* m16     = (__half*)(agg + (size_t)N_NODES * 32);// 6.4 MB (h0 mirror, then BN1 mirror)
    unsigned char* key = (unsigned char*)(m16 + (size_t)N_NODES * 32); // 3.2 MB
    int*    cmat    = (int*)(key + N_EDGES);                // LALLOC ints (~2.45 MB)
    float*  stats   = (float*)(cmat + LALLOC);              // 128 floats -- memset'd with cmat pad
    int*    t1      = (int*)(stats + 128);                  // 2560
    int*    offs    = t1 + 2560;                            // NPAD2+1
    int*    goff    = offs + NPAD2 + 1;                     // N_GRAPHS+1
    float*  gsum    = (float*)(goff + N_GRAPHS + 1);        // G*32
    float*  w1tp    = gsum + (size_t)N_GRAPHS * 32;         // 2*80*32
    float*  b1p     = w1tp + 2 * HPAD * 32;                 // 2*80
    float*  w2p     = b1p + 2 * HPAD;                       // 2*80*32

    int nb_nodes = (N_NODES + 255) / 256;
    int nb_vec   = (N_NODES * 8 + 255) / 256;

    // zero only the scan pad tail (168 ints) + stats (128 floats) — contiguous
    hipMemsetAsync(cmat + NBLK_TOT, 0, (size_t)(LALLOC - NBLK_TOT + 128) * sizeof(int), stream);
    k_encode<<<nb_nodes, 256, 0, stream>>>(x, node_w, node_b, h, m16);
    k_prep<<<(2 * HPAD * 32 + 2 * HPAD + 255) / 256, 256, 0, stream>>>(
        conv_w1, conv_b1, conv_w2, w1tp, b1p, w2p);
    k_goff<<<(N_GRAPHS + 1 + 255) / 256, 256, 0, stream>>>(batch, goff);

    ksA<<<NBLKA, 256, 0, stream>>>(ei, cmat);
    ks1<<<NS1, 256, 0, stream>>>(cmat, t1);
    ks2<NS1, 10><<<1, 256, 0, stream>>>(t1);
    ks3<<<NS1, 256, 0, stream>>>(cmat, t1);
    ksB<<<NBLKA, 256, 0, stream>>>(ei, eattr, cmat, buf1, key);
    ksC<<<NBKT, 512, 0, stream>>>(cmat, buf1, key, packed, offs);

    // layer 1: agg(h0) -> zin1(agg) -> mlp -> z1(agg) + stats[0:64] -> BN mirror m16
    k_agg<false><<<N_NODES * 32 / 256, 256, 0, stream>>>(packed, offs, edge_w, edge_b,
                                                         m16, h, stats, bn_g, bn_b, agg);
    k_mlp<<<N_NODES * 8 / 256, 256, 0, stream>>>(agg, w1tp, b1p, w2p, conv_b2, stats);
    k_bnh<<<nb_vec, 256, 0, stream>>>(agg, m16, stats, bn_g, bn_b);
    // layer 2: agg gathers BN1 mirror, self-term = relu(BN1(z1)) inline -> zin2(h) -> mlp -> z2(h) + stats[64:]
    k_agg<true><<<N_NODES * 32 / 256, 256, 0, stream>>>(packed, offs, edge_w, edge_b,
                                                        m16, agg, stats, bn_g, bn_b, h);
    k_mlp<<<N_NODES * 8 / 256, 256, 0, stream>>>(h, w1tp + HPAD * 32, b1p + HPAD,
                                                 w2p + HPAD * 32, conv_b2 + 32, stats + 64);
    // pool applies BN2+relu inline from z2
    k_pool2<<<(N_GRAPHS + 3) / 4, 256, 0, stream>>>(h, goff, stats + 64, bn_g + 32, bn_b + 32, gsum);
    k_head<<<(N_GRAPHS + 255) / 256, 256, 0, stream>>>(gsum, goff, lin1_w, lin1_b, lin2_w, lin2_b, out);
}

// Round 4
// 472.089 us; speedup vs baseline: 3.5751x; 1.2335x over previous
//
#include <hip/hip_runtime.h>
#include <hip/hip_fp16.h>

#define N_NODES 100000
#define N_EDGES 3200000
#define N_GRAPHS 5000
#define BN_EPS 1e-5f
#define HPAD 80        // hidden 75 padded to 80
#define CHUNK 2048     // edges per bucket-sort block
#define NBLKA 1563     // ceil(N_EDGES / CHUNK)
#define NBKT 392       // buckets of 256 nodes (dst >> 8)
#define NPAD2 (NBKT * 256)     // 100352
#define NBLK_TOT (NBKT * NBLKA)  // 612696
#define NS1 2394       // ceil(NBLK_TOT / 256)
#define LALLOC (NS1 * 256)
#define W1S 36         // sW1 row stride: 2-way bank alias only (free)

// ---------- node encoder: h = x @ node_w + node_b (fp32 + fp16 mirror) ----------
__global__ void k_encode(const float* __restrict__ x, const float* __restrict__ W,
                         const float* __restrict__ b, float* __restrict__ h,
                         __half* __restrict__ h16) {
    __shared__ float sW[448];
    __shared__ float sb[32];
    for (int i = threadIdx.x; i < 448; i += 256) sW[i] = W[i];
    if (threadIdx.x < 32) sb[threadIdx.x] = b[threadIdx.x];
    __syncthreads();
    int n = blockIdx.x * 256 + threadIdx.x;
    if (n >= N_NODES) return;
    float xi[14];
#pragma unroll
    for (int k = 0; k < 14; k++) xi[k] = x[n * 14 + k];
    float4* hp = (float4*)(h + (size_t)n * 32);
    __half2* hq = (__half2*)(h16 + (size_t)n * 32);
#pragma unroll
    for (int q = 0; q < 8; q++) {
        float4 acc;
        float* ap = (float*)&acc;
#pragma unroll
        for (int i = 0; i < 4; i++) {
            int c = q * 4 + i;
            float a = sb[c];
#pragma unroll
            for (int k = 0; k < 14; k++) a += xi[k] * sW[k * 32 + c];
            ap[i] = a;
        }
        hp[q] = acc;
        hq[q * 2 + 0] = __floats2half2_rn(acc.x, acc.y);
        hq[q * 2 + 1] = __floats2half2_rn(acc.z, acc.w);
    }
}

// ---------- weight prep ----------
__global__ void k_prep(const float* __restrict__ W1, const float* __restrict__ b1,
                       const float* __restrict__ W2,
                       float* __restrict__ w1tp, float* __restrict__ b1p,
                       float* __restrict__ w2p) {
    int i = blockIdx.x * 256 + threadIdx.x;
    if (i < 2 * HPAD * 32) {
        int l = i / (HPAD * 32), r = i % (HPAD * 32);
        int j = r / 32, c = r % 32;
        w1tp[i] = (j < 75) ? W1[l * 2400 + c * 75 + j] : 0.f;
        w2p[i]  = (j < 75) ? W2[l * 2400 + j * 32 + c] : 0.f;
    } else if (i < 2 * HPAD * 32 + 2 * HPAD) {
        int k = i - 2 * HPAD * 32;
        int l = k / HPAD, j = k % HPAD;
        b1p[k] = (j < 75) ? b1[l * 75 + j] : 0.f;
    }
}

// ---------- bucket sort phase A: per-chunk histogram (LDS atomics only) ----------
__global__ void __launch_bounds__(256) ksA(const int* __restrict__ ei, int* __restrict__ cmat) {
    __shared__ int lh[NBKT];
    for (int i = threadIdx.x; i < NBKT; i += 256) lh[i] = 0;
    __syncthreads();
    int b0 = blockIdx.x * CHUNK;
    for (int i = threadIdx.x; i < CHUNK; i += 256) {
        int e = b0 + i;
        if (e < N_EDGES) atomicAdd(&lh[ei[N_EDGES + e] >> 8], 1);
    }
    __syncthreads();
    for (int i = threadIdx.x; i < NBKT; i += 256)
        cmat[i * NBLKA + blockIdx.x] = lh[i];
}

// ---------- 3-kernel exclusive scan of cmat ----------
__global__ void ks1(const int* __restrict__ a, int* __restrict__ bs) {
    __shared__ int s[256];
    int i = blockIdx.x * 256 + threadIdx.x;
    s[threadIdx.x] = a[i];
    __syncthreads();
    for (int o = 128; o > 0; o >>= 1) {
        if (threadIdx.x < o) s[threadIdx.x] += s[threadIdx.x + o];
        __syncthreads();
    }
    if (threadIdx.x == 0) bs[blockIdx.x] = s[0];
}

template<int NSX, int VPTX>
__global__ void ks2(int* __restrict__ bs) {
    __shared__ int s[256];
    int t = threadIdx.x;
    int v[VPTX];
    int base = t * VPTX, sum = 0;
#pragma unroll
    for (int k = 0; k < VPTX; k++) {
        int idx = base + k;
        int x = (idx < NSX) ? bs[idx] : 0;
        v[k] = sum; sum += x;
    }
    s[t] = sum;
    __syncthreads();
    for (int o = 1; o < 256; o <<= 1) {
        int add = (t >= o) ? s[t - o] : 0;
        __syncthreads();
        s[t] += add;
        __syncthreads();
    }
    int excl = (t == 0) ? 0 : s[t - 1];
#pragma unroll
    for (int k = 0; k < VPTX; k++) {
        int idx = base + k;
        if (idx < NSX) bs[idx] = excl + v[k];
    }
}

__global__ void ks3(int* __restrict__ a, const int* __restrict__ bs) {
    __shared__ int s[256];
    int t = threadIdx.x, i = blockIdx.x * 256 + t;
    int v = a[i];
    s[t] = v;
    __syncthreads();
    for (int o = 1; o < 256; o <<= 1) {
        int add = (t >= o) ? s[t - o] : 0;
        __syncthreads();
        s[t] += add;
        __syncthreads();
    }
    a[i] = s[t] - v + bs[blockIdx.x];
}

// ---------- phase B: per-block counting sort in LDS, then coalesced drain (+key bytes) ----------
__global__ void __launch_bounds__(256) ksB(const int* __restrict__ ei, const float* __restrict__ ea,
                                           const int* __restrict__ cmat, float4* __restrict__ buf1,
                                           unsigned char* __restrict__ key) {
    __shared__ float4 rec[CHUNK];          // 32 KB
    __shared__ unsigned short sbkt[CHUNK]; // 4 KB
    __shared__ int lh[NBKT];
    __shared__ int lex[NBKT];
    __shared__ int gb[NBKT];
    __shared__ int sc[256];
    int t = threadIdx.x;
    int b0 = blockIdx.x * CHUNK;
    int nval = min(CHUNK, N_EDGES - b0);
    for (int i = t; i < NBKT; i += 256) lh[i] = 0;
    __syncthreads();
    for (int i = t; i < nval; i += 256)
        atomicAdd(&lh[ei[N_EDGES + b0 + i] >> 8], 1);
    __syncthreads();
    // scan 392 buckets: 2 per thread + 256-wide scan of thread totals
    int x0 = (t * 2 < NBKT) ? lh[t * 2] : 0;
    int x1 = (t * 2 + 1 < NBKT) ? lh[t * 2 + 1] : 0;
    int v0 = 0, v1 = x0, run = x0 + x1;
    sc[t] = run;
    __syncthreads();
    for (int o = 1; o < 256; o <<= 1) {
        int add = (t >= o) ? sc[t - o] : 0;
        __syncthreads();
        sc[t] += add;
        __syncthreads();
    }
    int excl = (t == 0) ? 0 : sc[t - 1];
    if (t * 2 < NBKT) {
        int base = excl + v0;
        lex[t * 2] = base; lh[t * 2] = base;
        gb[t * 2] = cmat[(t * 2) * NBLKA + blockIdx.x];
    }
    if (t * 2 + 1 < NBKT) {
        int base = excl + v1;
        lex[t * 2 + 1] = base; lh[t * 2 + 1] = base;
        gb[t * 2 + 1] = cmat[(t * 2 + 1) * NBLKA + blockIdx.x];
    }
    __syncthreads();
    for (int i = t; i < nval; i += 256) {
        int e = b0 + i;
        int src = ei[e], dst = ei[N_EDGES + e];
        float a0 = ea[(size_t)e * 3 + 0], a1 = ea[(size_t)e * 3 + 1], a2 = ea[(size_t)e * 3 + 2];
        int bkt = dst >> 8;
        int r = atomicAdd(&lh[bkt], 1);
        rec[r] = make_float4(a0, a1, a2, __int_as_float(src | ((dst & 255) << 17)));
        sbkt[r] = (unsigned short)bkt;
    }
    __syncthreads();
    for (int p = t; p < nval; p += 256) {
        int bkt = sbkt[p];
        int gp = gb[bkt] + (p - lex[bkt]);
        float4 r = rec[p];
        buf1[gp] = r;
        key[gp] = (unsigned char)(((unsigned)__float_as_int(r.w)) >> 17);
    }
}

// ---------- phase C: per-256-node-bucket exact CSR (LDS atomics, byte-key count pass) ----------
__global__ void __launch_bounds__(512) ksC(const int* __restrict__ cmat, const float4* __restrict__ buf1,
                                           const unsigned char* __restrict__ key,
                                           float4* __restrict__ packed, int* __restrict__ offs) {
    __shared__ int cnt[256];
    __shared__ int sc2[256];
    __shared__ int excl[256];
    int g = blockIdx.x, t = threadIdx.x;
    int bb = cmat[g * NBLKA];
    int be = (g == NBKT - 1) ? N_EDGES : cmat[(g + 1) * NBLKA];
    if (t < 256) cnt[t] = 0;
    __syncthreads();
    for (int j = bb + t; j < be; j += 512) atomicAdd(&cnt[key[j]], 1);
    __syncthreads();
    if (t < 256) sc2[t] = cnt[t];
    __syncthreads();
    for (int o = 1; o < 256; o <<= 1) {
        int add = 0;
        if (t < 256 && t >= o) add = sc2[t - o];
        __syncthreads();
        if (t < 256) sc2[t] += add;
        __syncthreads();
    }
    if (t < 256) {
        excl[t] = sc2[t] - cnt[t];
        offs[(g << 8) + t] = bb + excl[t];
        cnt[t] = 0;
    }
    if (g == NBKT - 1 && t == 0) offs[NPAD2] = N_EDGES;
    __syncthreads();
    for (int j = bb + t; j < be; j += 512) {
        float4 r = buf1[j];
        int bits = __float_as_int(r.w);
        int dl = bits >> 17;
        int rank = atomicAdd(&cnt[dl], 1);
        packed[bb + excl[dl] + rank] = make_float4(r.x, r.y, r.z, __int_as_float(bits & 0x1FFFF));
    }
}

// ---------- pull aggregation: 32 threads/node, fp16 gather, unroll-2; writes zin = self + agg ----------
// BN=true: self-term applies relu(BN1(z)) inline (fp32, exact)
template<bool BN>
__global__ void __launch_bounds__(256) k_agg(const float4* __restrict__ packed,
                                             const int* __restrict__ offs,
                                             const float* __restrict__ eW, const float* __restrict__ eb,
                                             const __half* __restrict__ h16,
                                             const float* __restrict__ hs,
                                             const float* __restrict__ stats,
                                             const float* __restrict__ bng, const float* __restrict__ bnb,
                                             float* __restrict__ zin) {
    int t = blockIdx.x * 256 + threadIdx.x;   // N_NODES*32 exact
    int n = t >> 5, s = t & 31;
    int q = s & 7, part = s >> 3;
    int c0 = q * 4;
    float w0[4], w1[4], w2[4], bb4[4];
#pragma unroll
    for (int i = 0; i < 4; i++) {
        w0[i] = eW[c0 + i];
        w1[i] = eW[32 + c0 + i];
        w2[i] = eW[64 + c0 + i];
        bb4[i] = eb[c0 + i];
    }
    int beg = offs[n], end = offs[n + 1];
    float acc0[4] = {0.f, 0.f, 0.f, 0.f};
    float acc1[4] = {0.f, 0.f, 0.f, 0.f};
    int j = beg + part;
    for (; j + 4 < end; j += 8) {
        float4 pa = packed[j];
        float4 pb = packed[j + 4];
        float2 ra = *(const float2*)(h16 + (size_t)__float_as_int(pa.w) * 32 + c0);
        float2 rb = *(const float2*)(h16 + (size_t)__float_as_int(pb.w) * 32 + c0);
        float2 a01 = __half22float2(*(__half2*)&ra.x);
        float2 a23 = __half22float2(*(__half2*)&ra.y);
        float2 b01 = __half22float2(*(__half2*)&rb.x);
        float2 b23 = __half22float2(*(__half2*)&rb.y);
        float ha4[4] = {a01.x, a01.y, a23.x, a23.y};
        float hb4[4] = {b01.x, b01.y, b23.x, b23.y};
#pragma unroll
        for (int i = 0; i < 4; i++) {
            acc0[i] += fmaxf(ha4[i] + pa.x * w0[i] + pa.y * w1[i] + pa.z * w2[i] + bb4[i], 0.f);
            acc1[i] += fmaxf(hb4[i] + pb.x * w0[i] + pb.y * w1[i] + pb.z * w2[i] + bb4[i], 0.f);
        }
    }
    if (j < end) {
        float4 p = packed[j];
        float2 r = *(const float2*)(h16 + (size_t)__float_as_int(p.w) * 32 + c0);
        float2 a01 = __half22float2(*(__half2*)&r.x);
        float2 a23 = __half22float2(*(__half2*)&r.y);
        float hp4[4] = {a01.x, a01.y, a23.x, a23.y};
#pragma unroll
        for (int i = 0; i < 4; i++)
            acc0[i] += fmaxf(hp4[i] + p.x * w0[i] + p.y * w1[i] + p.z * w2[i] + bb4[i], 0.f);
    }
    float acc[4];
#pragma unroll
    for (int i = 0; i < 4; i++) {
        acc[i] = acc0[i] + acc1[i];
        acc[i] += __shfl_xor(acc[i], 8, 64);
        acc[i] += __shfl_xor(acc[i], 16, 64);
    }
    if (part == 0) {
        float4 hq = *(const float4*)(hs + (size_t)n * 32 + c0);   // coalesced, L2-warm
        float* hp = (float*)&hq;
        float sv[4];
        if (BN) {
            const float invN = 1.0f / (float)N_NODES;
#pragma unroll
            for (int i = 0; i < 4; i++) {
                int c = c0 + i;
                float mu = stats[c] * invN;
                float var = stats[32 + c] * invN - mu * mu;
                float scl = bng[c] / sqrtf(var + BN_EPS);
                float sft = bnb[c] - mu * scl;
                sv[i] = fmaxf(hp[i] * scl + sft, 0.f);
            }
        } else {
#pragma unroll
            for (int i = 0; i < 4; i++) sv[i] = hp[i];
        }
        *(float4*)(zin + (size_t)n * 32 + c0) =
            make_float4(acc[0] + sv[0], acc[1] + sv[1], acc[2] + sv[2], acc[3] + sv[3]);
    }
}

// ---------- fused MLP: z = relu(zin@W1+b1)@W2+b2, written over zin ----------
__global__ void __launch_bounds__(256, 4) k_mlp(float* __restrict__ zio,
                                                const float* __restrict__ W1, const float* __restrict__ B1,
                                                const float* __restrict__ W2, const float* __restrict__ b2) {
    __shared__ float sW1[HPAD * W1S];  // stride 36 (2-way bank alias = free)
    __shared__ float sW2[2560];
    __shared__ float sB1[80];
    __shared__ float sb2[32];
    __shared__ float hidL[32 * 84];
    for (int i = threadIdx.x; i < 2560; i += 256) {
        int j = i >> 5, c = i & 31;
        sW1[j * W1S + c] = W1[i];
        sW2[i] = W2[i];
    }
    if (threadIdx.x < 80) sB1[threadIdx.x] = B1[threadIdx.x];
    if (threadIdx.x < 32) sb2[threadIdx.x] = b2[threadIdx.x];
    __syncthreads();
    unsigned t = blockIdx.x * 256 + threadIdx.x;
    unsigned lane = threadIdx.x & 63;
    unsigned wv = threadIdx.x >> 6;
    unsigned oct = lane >> 3;
    unsigned nd = lane & 7;
    unsigned n = (t >> 6) * 8 + nd;
    const float4* ap = (const float4*)(zio + (size_t)n * 32);
    float zc[32];
#pragma unroll
    for (int q = 0; q < 8; q++) {
        float4 av = ap[q];
        zc[q * 4 + 0] = av.x;
        zc[q * 4 + 1] = av.y;
        zc[q * 4 + 2] = av.z;
        zc[q * 4 + 3] = av.w;
    }
    float hid[10];
#pragma unroll
    for (int i = 0; i < 10; i++) {
        int j = (int)oct * 10 + i;
        const float4* wp = (const float4*)(sW1 + j * W1S);
        float a0 = 0.f, a1 = 0.f, a2 = 0.f, a3 = 0.f;
#pragma unroll
        for (int q = 0; q < 8; q++) {
            float4 wv4 = wp[q];
            a0 += zc[q * 4 + 0] * wv4.x;
            a1 += zc[q * 4 + 1] * wv4.y;
            a2 += zc[q * 4 + 2] * wv4.z;
            a3 += zc[q * 4 + 3] * wv4.w;
        }
        hid[i] = fmaxf(sB1[j] + ((a0 + a1) + (a2 + a3)), 0.f);
    }
    float* hrow = &hidL[(wv * 8 + nd) * 84];
#pragma unroll
    for (int i = 0; i < 10; i++) hrow[oct * 10 + i] = hid[i];
    float4 zo = *(const float4*)(sb2 + oct * 4);
    const float4* hv4 = (const float4*)hrow;
#pragma unroll
    for (int k = 0; k < 20; k++) {
        float4 hv = hv4[k];
        const float* wr = sW2 + (k * 4) * 32 + oct * 4;
        float4 wa = *(const float4*)(wr);
        float4 wb = *(const float4*)(wr + 32);
        float4 wc = *(const float4*)(wr + 64);
        float4 wd = *(const float4*)(wr + 96);
        zo.x += hv.x * wa.x + hv.y * wb.x + hv.z * wc.x + hv.w * wd.x;
        zo.y += hv.x * wa.y + hv.y * wb.y + hv.z * wc.y + hv.w * wd.y;
        zo.z += hv.x * wa.z + hv.y * wb.z + hv.z * wc.z + hv.w * wd.z;
        zo.w += hv.x * wa.w + hv.y * wb.w + hv.z * wc.w + hv.w * wd.w;
    }
    *(float4*)(zio + (size_t)n * 32 + oct * 4) = zo;
}

// ---------- BN stats (standalone, 256 blocks -> low atomic contention) ----------
__global__ void __launch_bounds__(256) k_stats(const float* __restrict__ z, float* __restrict__ stats) {
    __shared__ float ls[4 * 64];
    int tid = threadIdx.x;
    int c = tid & 31;
    float s = 0.f, s2 = 0.f;
    for (int e = blockIdx.x * 256 + tid; e < N_NODES * 32; e += 256 * 256) {
        float v = z[e];
        s += v; s2 += v * v;
    }
    s += __shfl_down(s, 32, 64);
    s2 += __shfl_down(s2, 32, 64);
    int wave = tid >> 6, lane = tid & 63;
    if (lane < 32) { ls[wave * 64 + c] = s; ls[wave * 64 + 32 + c] = s2; }
    __syncthreads();
    if (tid < 64) {
        float a = ls[tid] + ls[64 + tid] + ls[128 + tid] + ls[192 + tid];
        atomicAdd(&stats[tid], a);
    }
}

// ---------- BN apply + relu, fp16 mirror only (layer-1) ----------
__global__ void k_bnh(const float* __restrict__ z, __half* __restrict__ m,
                      const float* __restrict__ stats, const float* __restrict__ g,
                      const float* __restrict__ b) {
    int t = blockIdx.x * 256 + threadIdx.x;
    if (t >= N_NODES * 8) return;
    int q = t & 7;
    float4 zv = ((const float4*)z)[t];
    float* zp = (float*)&zv;
    float ov[4];
    const float invN = 1.0f / (float)N_NODES;
#pragma unroll
    for (int i = 0; i < 4; i++) {
        int c = q * 4 + i;
        float mu = stats[c] * invN;
        float var = stats[32 + c] * invN - mu * mu;
        float sc = g[c] / sqrtf(var + BN_EPS);
        ov[i] = fmaxf((zp[i] - mu) * sc + b[c], 0.f);
    }
    __half2* hq = (__half2*)(m + (size_t)t * 4);
    hq[0] = __floats2half2_rn(ov[0], ov[1]);
    hq[1] = __floats2half2_rn(ov[2], ov[3]);
}

// ---------- graph offsets (batch is sorted) ----------
__global__ void k_goff(const int* __restrict__ batch, int* __restrict__ goff) {
    int g = blockIdx.x * 256 + threadIdx.x;
    if (g > N_GRAPHS) return;
    int lo = 0, hi = N_NODES;
    while (lo < hi) {
        int mid = (lo + hi) >> 1;
        if (batch[mid] < g) lo = mid + 1; else hi = mid;
    }
    goff[g] = lo;
}

// ---------- mean-pool with fused BN2+relu: one wave per graph ----------
__global__ void __launch_bounds__(256) k_pool2(const float* __restrict__ z, const int* __restrict__ goff,
                                               const float* __restrict__ stats,
                                               const float* __restrict__ g, const float* __restrict__ b,
                                               float* __restrict__ gsum) {
    int wid = threadIdx.x >> 6, lane = threadIdx.x & 63;
    int gi = blockIdx.x * 4 + wid;
    if (gi >= N_GRAPHS) return;
    int s = goff[gi], e = goff[gi + 1];
    int c = lane & 31, half = lane >> 5;
    const float invN = 1.0f / (float)N_NODES;
    float mu = stats[c] * invN;
    float var = stats[32 + c] * invN - mu * mu;
    float scl = g[c] / sqrtf(var + BN_EPS);
    float sft = b[c] - mu * scl;
    float acc = 0.f;
    for (int n = s + half; n < e; n += 2)
        acc += fmaxf(z[(size_t)n * 32 + c] * scl + sft, 0.f);
    acc += __shfl_down(acc, 32, 64);
    if (lane < 32) gsum[(size_t)gi * 32 + c] = acc;
}

__global__ void k_head(const float* __restrict__ gsum, const int* __restrict__ goff,
                       const float* __restrict__ W1, const float* __restrict__ b1,
                       const float* __restrict__ W2, const float* __restrict__ b2,
                       float* __restrict__ out) {
    __shared__ float sW1[512], sb1[16], sW2[32], sb2[2];
    for (int i = threadIdx.x; i < 512; i += 256) sW1[i] = W1[i];
    if (threadIdx.x < 16) sb1[threadIdx.x] = b1[threadIdx.x];
    if (threadIdx.x < 32) sW2[threadIdx.x] = W2[threadIdx.x];
    if (threadIdx.x < 2) sb2[threadIdx.x] = b2[threadIdx.x];
    __syncthreads();
    int gI = blockIdx.x * 256 + threadIdx.x;
    if (gI >= N_GRAPHS) return;
    float cnt = (float)(goff[gI + 1] - goff[gI]);
    float inv = 1.0f / fmaxf(cnt, 1.0f);
    float gx[32];
#pragma unroll
    for (int c = 0; c < 32; c++) gx[c] = gsum[(size_t)gI * 32 + c] * inv;
    float hid[16];
#pragma unroll
    for (int j = 0; j < 16; j++) {
        float a = sb1[j];
#pragma unroll
        for (int c = 0; c < 32; c++) a += gx[c] * sW1[c * 16 + j];
        hid[j] = fmaxf(a, 0.f);
    }
#pragma unroll
    for (int o = 0; o < 2; o++) {
        float a = sb2[o];
#pragma unroll
        for (int j = 0; j < 16; j++) a += hid[j] * sW2[j * 2 + o];
        out[(size_t)gI * 2 + o] = a;
    }
}

extern "C" void kernel_launch(void* const* d_in, const int* in_sizes, int n_in,
                              void* d_out, int out_size, void* d_ws, size_t ws_size,
                              hipStream_t stream) {
    const float* x       = (const float*)d_in[0];
    const int*   ei      = (const int*)d_in[1];
    const float* eattr   = (const float*)d_in[2];
    const int*   batch   = (const int*)d_in[3];
    const float* node_w  = (const float*)d_in[4];
    const float* node_b  = (const float*)d_in[5];
    const float* edge_w  = (const float*)d_in[6];
    const float* edge_b  = (const float*)d_in[7];
    const float* conv_w1 = (const float*)d_in[8];
    const float* conv_b1 = (const float*)d_in[9];
    const float* conv_w2 = (const float*)d_in[10];
    const float* conv_b2 = (const float*)d_in[11];
    const float* bn_g    = (const float*)d_in[12];
    const float* bn_b    = (const float*)d_in[13];
    const float* lin1_w  = (const float*)d_in[14];
    const float* lin1_b  = (const float*)d_in[15];
    const float* lin2_w  = (const float*)d_in[16];
    const float* lin2_b  = (const float*)d_in[17];
    float* out = (float*)d_out;

    float4* buf1    = (float4*)d_ws;                        // 51.2 MB
    float4* packed  = buf1 + N_EDGES;                       // 51.2 MB
    float*  h       = (float*)(packed + N_EDGES);           // 12.8 MB (h0, then zin2/z2)
    float*  agg     = h + (size_t)N_NODES * 32;             // 12.8 MB (zin1/z1)
    __half* m16     = (__half*)(agg + (size_t)N_NODES * 32);// 6.4 MB (h0 mirror, then BN1 mirror)
    unsigned char* key = (unsigned char*)(m16 + (size_t)N_NODES * 32); // 3.2 MB
    int*    cmat    = (int*)(key + N_EDGES);                // LALLOC ints (~2.45 MB)
    float*  stats   = (float*)(cmat + LALLOC);              // 128 floats -- memset'd with cmat pad
    int*    t1      = (int*)(stats + 128);                  // 2560
    int*    offs    = t1 + 2560;                            // NPAD2+1
    int*    goff    = offs + NPAD2 + 1;                     // N_GRAPHS+1
    float*  gsum    = (float*)(goff + N_GRAPHS + 1);        // G*32
    float*  w1tp    = gsum + (size_t)N_GRAPHS * 32;         // 2*80*32
    float*  b1p     = w1tp + 2 * HPAD * 32;                 // 2*80
    float*  w2p     = b1p + 2 * HPAD;                       // 2*80*32

    int nb_nodes = (N_NODES + 255) / 256;
    int nb_vec   = (N_NODES * 8 + 255) / 256;

    // zero only the scan pad tail (168 ints) + stats (128 floats) — contiguous
    hipMemsetAsync(cmat + NBLK_TOT, 0, (size_t)(LALLOC - NBLK_TOT + 128) * sizeof(int), stream);
    k_encode<<<nb_nodes, 256, 0, stream>>>(x, node_w, node_b, h, m16);
    k_prep<<<(2 * HPAD * 32 + 2 * HPAD + 255) / 256, 256, 0, stream>>>(
        conv_w1, conv_b1, conv_w2, w1tp, b1p, w2p);
    k_goff<<<(N_GRAPHS + 1 + 255) / 256, 256, 0, stream>>>(batch, goff);

    ksA<<<NBLKA, 256, 0, stream>>>(ei, cmat);
    ks1<<<NS1, 256, 0, stream>>>(cmat, t1);
    ks2<NS1, 10><<<1, 256, 0, stream>>>(t1);
    ks3<<<NS1, 256, 0, stream>>>(cmat, t1);
    ksB<<<NBLKA, 256, 0, stream>>>(ei, eattr, cmat, buf1, key);
    ksC<<<NBKT, 512, 0, stream>>>(cmat, buf1, key, packed, offs);

    // layer 1: agg(h0) -> zin1(agg) -> mlp -> z1(agg); stats[0:64]; BN mirror m16
    k_agg<false><<<N_NODES * 32 / 256, 256, 0, stream>>>(packed, offs, edge_w, edge_b,
                                                         m16, h, stats, bn_g, bn_b, agg);
    k_mlp<<<N_NODES * 8 / 256, 256, 0, stream>>>(agg, w1tp, b1p, w2p, conv_b2);
    k_stats<<<256, 256, 0, stream>>>(agg, stats);
    k_bnh<<<nb_vec, 256, 0, stream>>>(agg, m16, stats, bn_g, bn_b);
    // layer 2: agg gathers BN1 mirror, self-term = relu(BN1(z1)) inline -> zin2(h) -> mlp -> z2(h); stats[64:]
    k_agg<true><<<N_NODES * 32 / 256, 256, 0, stream>>>(packed, offs, edge_w, edge_b,
                                                        m16, agg, stats, bn_g, bn_b, h);
    k_mlp<<<N_NODES * 8 / 256, 256, 0, stream>>>(h, w1tp + HPAD * 32, b1p + HPAD,
                                                 w2p + HPAD * 32, conv_b2 + 32);
    k_stats<<<256, 256, 0, stream>>>(h, stats + 64);
    // pool applies BN2+relu inline from z2
    k_pool2<<<(N_GRAPHS + 3) / 4, 256, 0, stream>>>(h, goff, stats + 64, bn_g + 32, bn_b + 32, gsum);
    k_head<<<(N_GRAPHS + 255) / 256, 256, 0, stream>>>(gsum, goff, lin1_w, lin1_b, lin2_w, lin2_b, out);
}